// Round 11
// baseline (368.583 us; speedup 1.0000x reference)
//
#include <hip/hip_runtime.h>
#include <math.h>

#define NN 100000   // nodes
#define NE 400000   // edges
#define NG 2000     // graphs
#define F0 84       // num_features_xd
#define F2 840      // F0*10
#define FH 1024     // fc hidden
#define FO 384      // fc out
#define NT2 6250    // row tiles (NN/16)

typedef __attribute__((ext_vector_type(8))) short bf16x8;
typedef __attribute__((ext_vector_type(4))) short bf16x4;
typedef __attribute__((ext_vector_type(4))) float f32x4;

__device__ inline short f2bf(float f) {
    union { float f; unsigned u; } v; v.f = f;
    unsigned r = (v.u + 0x7FFFu + ((v.u >> 16) & 1u)) >> 16;
    return (short)r;
}
__device__ inline float b2f(short s) {
    union { unsigned u; float f; } v;
    v.u = ((unsigned)(unsigned short)s) << 16;
    return v.f;
}

// ---- pack geometry ----
#define S1 (8*3*64)
#define S2 (56*3*64)
#define S3 (64*53*64)
#define S4 (24*32*64)
#define PACK_TOT (S1 + S2 + S3 + S4)     // 278528
#define NB_FILL 1563                     // ceil(NE/256)
#define NB_CAST 4688                     // ceil(NN*12/256)
#define NB_PACK 1088                     // ceil(PACK_TOT/256)

__device__ inline void pack_one(const float* __restrict__ W, short* __restrict__ P,
                                int K, int N, int KB, int CT, int idx) {
    int lane = idx & 63;
    int t    = idx >> 6;
    int kb   = t % KB;
    int ct   = t / KB;
    int col  = ct * 16 + (lane & 15);
    int k0   = kb * 32 + ((lane >> 4) << 3);
    bf16x8 v;
#pragma unroll
    for (int j = 0; j < 8; ++j) {
        int k = k0 + j;
        float f = (k < K && col < N) ? W[(size_t)k * N + col] : 0.f;
        v[j] = f2bf(f);
    }
    *reinterpret_cast<bf16x8*>(P + (size_t)idx * 8) = v;
}

// ---- edge degree histogram (scan critical path starts here) ----
__global__ void edge_deg(const int* __restrict__ dst, int* __restrict__ deg) {
    int e = blockIdx.x * blockDim.x + threadIdx.x;
    if (e < NE) atomicAdd(&deg[dst[e]], 1);
}

// ---- scan phase 1 ----
__global__ void scan_ph1(const int* __restrict__ deg, int* __restrict__ rowptr,
                         int* __restrict__ bsum) {
    __shared__ int s[1024];
    int t = threadIdx.x;
    int i = blockIdx.x * 1024 + t;
    int v = (i < NN) ? deg[i] : 0;
    s[t] = v;
    __syncthreads();
    for (int d = 1; d < 1024; d <<= 1) {
        int u = (t >= d) ? s[t - d] : 0;
        __syncthreads();
        s[t] += u;
        __syncthreads();
    }
    if (i < NN) rowptr[i] = s[t] - v;
    if (t == 1023) bsum[blockIdx.x] = s[t];
}

// ---- scan phase 2+3 (also zeroes cnt for edge_fill) ----
__global__ void scan_ph23(int* __restrict__ rowptr, const int* __restrict__ bsum,
                          int* __restrict__ cnt, int nb) {
    __shared__ int s[128];
    int t = threadIdx.x;
    int b = blockIdx.x;
    if (t < 128) s[t] = (t < b && t < nb) ? bsum[t] : 0;
    __syncthreads();
    for (int d = 64; d >= 1; d >>= 1) {
        if (t < d) s[t] += s[t + d];
        __syncthreads();
    }
    int off = s[0];
    int i = b * 1024 + t;
    if (i < NN) {
        rowptr[i] += off;
        cnt[i] = 0;
    }
    if (i == 0) rowptr[NN] = NE;
}

// ---- edge_fill || cast_x || pack_all (off the scan critical path) ----
__global__ void fill_cast_pack(const int* __restrict__ src, const int* __restrict__ dst,
                               const int* __restrict__ rowptr, int* __restrict__ cnt,
                               int* __restrict__ eid,
                               const float* __restrict__ x, short* __restrict__ Xb,
                               const float* __restrict__ W1, short* __restrict__ P1,
                               const float* __restrict__ W2, short* __restrict__ P2,
                               const float* __restrict__ Wf1, short* __restrict__ P3,
                               const float* __restrict__ Wf2, short* __restrict__ P4) {
    int bid = blockIdx.x;
    if (bid < NB_FILL) {
        int e = bid * 256 + threadIdx.x;
        if (e < NE) {
            int d = dst[e];
            int p = rowptr[d] + atomicAdd(&cnt[d], 1);
            eid[p] = src[e];
        }
        return;
    }
    bid -= NB_FILL;
    if (bid < NB_CAST) {
        int idx = bid * 256 + threadIdx.x;
        if (idx < NN * 12) {
            int n = idx / 12;
            int c = idx - n * 12;
            int k0 = c * 8;
            bf16x8 v;
#pragma unroll
            for (int j = 0; j < 8; ++j) {
                int k = k0 + j;
                v[j] = (k < F0) ? f2bf(x[(size_t)n * F0 + k]) : (short)0;
            }
            *reinterpret_cast<bf16x8*>(Xb + (size_t)n * 96 + k0) = v;
        }
        return;
    }
    bid -= NB_CAST;
    int idx = bid * 256 + threadIdx.x;
    if (idx < S1) { pack_one(W1, P1, F0, F0, 3, 8, idx); return; }
    idx -= S1;
    if (idx < S2) { pack_one(W2, P2, F0, F2, 3, 56, idx); return; }
    idx -= S2;
    if (idx < S3) { pack_one(Wf1, P3, 1680, FH, 53, 64, idx); return; }
    idx -= S3;
    if (idx < S4) { pack_one(Wf2, P4, FH, FO, 32, 24, idx); return; }
}

// ---- gather item, 4-elem granularity: 384 items per 16-row tile ----
// item = r*24 + c4; k0 = 4*c4; writes 8B into fragment slot.
__device__ inline void gather_item4(const short* __restrict__ H,
                                    const int* __restrict__ rowptr,
                                    const int* __restrict__ eid,
                                    int n, int r, int c4, short* __restrict__ ldsTile) {
    int k0 = c4 * 4;
    bf16x4 sv = *reinterpret_cast<const bf16x4*>(H + (size_t)n * 96 + k0);
    float acc[4];
#pragma unroll
    for (int j = 0; j < 4; ++j) acc[j] = b2f(sv[j]);
    int e0 = rowptr[n], e1 = rowptr[n + 1];
    for (int e = e0; e < e1; ++e) {
        int s = eid[e];
        bf16x4 v = *reinterpret_cast<const bf16x4*>(H + (size_t)s * 96 + k0);
#pragma unroll
        for (int j = 0; j < 4; ++j) acc[j] += b2f(v[j]);
    }
    bf16x4 o;
#pragma unroll
    for (int j = 0; j < 4; ++j) o[j] = f2bf(acc[j]);
    int kb = k0 >> 5;
    int q  = (k0 >> 3) & 3;
    int h  = k0 & 7;
    *reinterpret_cast<bf16x4*>(&ldsTile[kb * 512 + (q * 16 + r) * 8 + h]) = o;
}

// ---- conv1 fused: 8 waves (512 thr), one 16-row tile, CTW=1 (8 ct slots) ----
template <int CTW, bool OUTBF16>
__global__ __launch_bounds__(512) void conv_fused(
        const short* __restrict__ H, const int* __restrict__ rowptr,
        const int* __restrict__ eid, const short* __restrict__ Bp,
        const float* __restrict__ bias, void* __restrict__ Cout,
        int Nbias, int ldc, int ncols) {
    __shared__ short Alds[3 * 512];
    int rt = blockIdx.x;
    int t  = threadIdx.x;

    if (t < 384) {
        int r  = t / 24;
        int c4 = t - r * 24;
        gather_item4(H, rowptr, eid, rt * 16 + r, r, c4, Alds);
    }
    __syncthreads();

    int wave = t >> 6;
    int lane = t & 63;
    f32x4 acc[CTW];
#pragma unroll
    for (int u = 0; u < CTW; ++u) acc[u] = (f32x4){0.f, 0.f, 0.f, 0.f};
    const short* Bbase = Bp + (size_t)(wave * CTW) * 3 * 512 + lane * 8;
#pragma unroll
    for (int kb = 0; kb < 3; ++kb) {
        bf16x8 a = *reinterpret_cast<const bf16x8*>(&Alds[kb * 512 + lane * 8]);
#pragma unroll
        for (int u = 0; u < CTW; ++u) {
            bf16x8 b = *reinterpret_cast<const bf16x8*>(Bbase + ((size_t)u * 3 + kb) * 512);
            acc[u] = __builtin_amdgcn_mfma_f32_16x16x32_bf16(a, b, acc[u], 0, 0, 0);
        }
    }
    int row0 = rt * 16 + ((lane >> 4) << 2);
#pragma unroll
    for (int u = 0; u < CTW; ++u) {
        int col = (wave * CTW + u) * 16 + (lane & 15);
        float bi = (col < Nbias) ? bias[col] : 0.f;
        if (col < ncols) {
#pragma unroll
            for (int r = 0; r < 4; ++r) {
                float v = fmaxf(acc[u][r] + bi, 0.f);
                if (OUTBF16) ((short*)Cout)[(size_t)(row0 + r) * ldc + col] = f2bf(v);
                else         ((float*)Cout)[(size_t)(row0 + r) * ldc + col] = v;
            }
        }
    }
}

// ---- conv2: 8 waves x CTW=7 (512 threads), one 16-row tile, partial pool ----
__global__ __launch_bounds__(512) void conv2_part(
        const short* __restrict__ H, const int* __restrict__ rowptr,
        const int* __restrict__ eid, const short* __restrict__ Bp,
        const float* __restrict__ bias, float* __restrict__ h2,
        float* __restrict__ Pmax, float* __restrict__ Psum) {
    __shared__ short Alds[3 * 512];
    int rt = blockIdx.x;
    int t  = threadIdx.x;

    if (t < 384) {
        int r  = t / 24;
        int c4 = t - r * 24;
        gather_item4(H, rowptr, eid, rt * 16 + r, r, c4, Alds);
    }
    __syncthreads();

    int wave = t >> 6;   // 0..7
    int lane = t & 63;
    f32x4 acc[7];
#pragma unroll
    for (int u = 0; u < 7; ++u) acc[u] = (f32x4){0.f, 0.f, 0.f, 0.f};
    const short* Bbase = Bp + (size_t)(wave * 7) * 3 * 512 + lane * 8;
#pragma unroll
    for (int kb = 0; kb < 3; ++kb) {
        bf16x8 a = *reinterpret_cast<const bf16x8*>(&Alds[kb * 512 + lane * 8]);
#pragma unroll
        for (int u = 0; u < 7; ++u) {
            bf16x8 b = *reinterpret_cast<const bf16x8*>(Bbase + ((size_t)u * 3 + kb) * 512);
            acc[u] = __builtin_amdgcn_mfma_f32_16x16x32_bf16(a, b, acc[u], 0, 0, 0);
        }
    }
    int row0 = rt * 16 + ((lane >> 4) << 2);
#pragma unroll
    for (int u = 0; u < 7; ++u) {
        int col = (wave * 7 + u) * 16 + (lane & 15);
        if (col < F2) {
            float bi = bias[col];
            float m = -INFINITY, sm = 0.f;
#pragma unroll
            for (int r = 0; r < 4; ++r) {
                float v = fmaxf(acc[u][r] + bi, 0.f);
                h2[(size_t)(row0 + r) * F2 + col] = v;
                m = fmaxf(m, v);
                sm += v;
            }
            m = fmaxf(m, __shfl_xor(m, 16));
            m = fmaxf(m, __shfl_xor(m, 32));
            sm += __shfl_xor(sm, 16);
            sm += __shfl_xor(sm, 32);
            if (lane < 16) {
                Pmax[(size_t)rt * F2 + col] = m;
                Psum[(size_t)rt * F2 + col] = sm;
            }
        }
    }
}

// ---- pool: per graph; full tiles from partials, boundary rows from h2 ----
__global__ void pool_kernel(const float* __restrict__ h2,
                            const int* __restrict__ batch,
                            const float* __restrict__ Pmax,
                            const float* __restrict__ Psum,
                            short* __restrict__ A3) {
    int g = blockIdx.x;
    int t = threadIdx.x;  // 256
    __shared__ int se[2];
    if (t < 2) {
        int target = g + t;
        int lo = 0, hi = NN;
        while (lo < hi) {
            int mid = (lo + hi) >> 1;
            if (batch[mid] < target) lo = mid + 1; else hi = mid;
        }
        se[t] = lo;
    }
    __syncthreads();
    int s = se[0], e = se[1];
    int t0 = (s + 15) >> 4;   // first full tile
    int t1 = e >> 4;          // end of full tiles
    if (t < 210) {
        int c4 = t * 4;
        float sm0 = 0.f, sm1 = 0.f, sm2 = 0.f, sm3 = 0.f;
        float mx0 = -INFINITY, mx1 = -INFINITY, mx2 = -INFINITY, mx3 = -INFINITY;
        if (t1 >= t0) {
            for (int tile = t0; tile < t1; ++tile) {
                float4 pm = *reinterpret_cast<const float4*>(Pmax + (size_t)tile * F2 + c4);
                float4 ps = *reinterpret_cast<const float4*>(Psum + (size_t)tile * F2 + c4);
                mx0 = fmaxf(mx0, pm.x); mx1 = fmaxf(mx1, pm.y);
                mx2 = fmaxf(mx2, pm.z); mx3 = fmaxf(mx3, pm.w);
                sm0 += ps.x; sm1 += ps.y; sm2 += ps.z; sm3 += ps.w;
            }
            for (int n = s; n < (t0 << 4); ++n) {
                float4 v = *reinterpret_cast<const float4*>(h2 + (size_t)n * F2 + c4);
                sm0 += v.x; sm1 += v.y; sm2 += v.z; sm3 += v.w;
                mx0 = fmaxf(mx0, v.x); mx1 = fmaxf(mx1, v.y);
                mx2 = fmaxf(mx2, v.z); mx3 = fmaxf(mx3, v.w);
            }
            for (int n = (t1 << 4); n < e; ++n) {
                float4 v = *reinterpret_cast<const float4*>(h2 + (size_t)n * F2 + c4);
                sm0 += v.x; sm1 += v.y; sm2 += v.z; sm3 += v.w;
                mx0 = fmaxf(mx0, v.x); mx1 = fmaxf(mx1, v.y);
                mx2 = fmaxf(mx2, v.z); mx3 = fmaxf(mx3, v.w);
            }
        } else {
            for (int n = s; n < e; ++n) {
                float4 v = *reinterpret_cast<const float4*>(h2 + (size_t)n * F2 + c4);
                sm0 += v.x; sm1 += v.y; sm2 += v.z; sm3 += v.w;
                mx0 = fmaxf(mx0, v.x); mx1 = fmaxf(mx1, v.y);
                mx2 = fmaxf(mx2, v.z); mx3 = fmaxf(mx3, v.w);
            }
        }
        short* xr = A3 + (size_t)g * 1696;
        short4 mo, so;
        mo.x = f2bf(mx0); mo.y = f2bf(mx1); mo.z = f2bf(mx2); mo.w = f2bf(mx3);
        so.x = f2bf(sm0); so.y = f2bf(sm1); so.z = f2bf(sm2); so.w = f2bf(sm3);
        *reinterpret_cast<short4*>(xr + c4)      = mo;
        *reinterpret_cast<short4*>(xr + F2 + c4) = so;
    }
    if (t >= 210 && t < 214) {
        short4 z = {0, 0, 0, 0};
        *reinterpret_cast<short4*>(A3 + (size_t)g * 1696 + 1680 + (t - 210) * 4) = z;
    }
}

// ---- plain MFMA GEMM (fc head) ----
template <int CTW, bool RELU, bool OUTBF16>
__global__ void gemmN(const short* __restrict__ A, const short* __restrict__ Bp,
                      const float* __restrict__ bias, void* __restrict__ Cout,
                      int Kp, int Nbias, int ldc, int ncols,
                      int rowTiles, int ctGroups) {
    int gid = blockIdx.x * blockDim.x + threadIdx.x;
    int w   = gid >> 6;
    if (w >= rowTiles * ctGroups) return;
    int lane = gid & 63;
    int rt = w / ctGroups;
    int cg = w - rt * ctGroups;
    int KB = Kp >> 5;
    const short* Ap = A + (size_t)(rt * 16 + (lane & 15)) * Kp + ((lane >> 4) << 3);
    const short* Bbase = Bp + (size_t)(cg * CTW) * KB * 512 + lane * 8;
    f32x4 acc[CTW];
#pragma unroll
    for (int u = 0; u < CTW; ++u) acc[u] = (f32x4){0.f, 0.f, 0.f, 0.f};
    for (int kb = 0; kb < KB; ++kb) {
        bf16x8 a = *reinterpret_cast<const bf16x8*>(Ap + kb * 32);
#pragma unroll
        for (int u = 0; u < CTW; ++u) {
            bf16x8 b = *reinterpret_cast<const bf16x8*>(Bbase + ((size_t)u * KB + kb) * 512);
            acc[u] = __builtin_amdgcn_mfma_f32_16x16x32_bf16(a, b, acc[u], 0, 0, 0);
        }
    }
    int row0 = rt * 16 + ((lane >> 4) << 2);
#pragma unroll
    for (int u = 0; u < CTW; ++u) {
        int col = (cg * CTW + u) * 16 + (lane & 15);
        float bi = (col < Nbias) ? bias[col] : 0.f;
        if (col < ncols) {
#pragma unroll
            for (int r = 0; r < 4; ++r) {
                int row = row0 + r;
                float v = acc[u][r] + bi;
                if (RELU) v = fmaxf(v, 0.f);
                if (OUTBF16) ((short*)Cout)[(size_t)row * ldc + col] = f2bf(v);
                else         ((float*)Cout)[(size_t)row * ldc + col] = v;
            }
        }
    }
}

extern "C" void kernel_launch(void* const* d_in, const int* in_sizes, int n_in,
                              void* d_out, int out_size, void* d_ws, size_t ws_size,
                              hipStream_t stream) {
    const float* x    = (const float*)d_in[0];
    const int*   ei   = (const int*)d_in[1];
    const int*   batch= (const int*)d_in[2];
    const float* W1   = (const float*)d_in[3];
    const float* b1   = (const float*)d_in[4];
    const float* W2   = (const float*)d_in[5];
    const float* b2   = (const float*)d_in[6];
    const float* Wf1  = (const float*)d_in[7];
    const float* bf1  = (const float*)d_in[8];
    const float* Wf2  = (const float*)d_in[9];
    const float* bf2  = (const float*)d_in[10];

    const int* src = ei;
    const int* dst = ei + NE;

    float* xg_out = (float*)d_out;                    // [NG, FO]
    float* h2     = (float*)d_out + (size_t)NG * FO;  // [NN, F2] fp32

    // workspace layout
    short* Xb   = (short*)d_ws;                        // NN*96
    short* h1   = Xb + (size_t)NN * 96;                // NN*96
    short* A3   = h1 + (size_t)NN * 96;                // NG*1696
    short* fc1o = A3 + (size_t)NG * 1696;              // NG*1024
    short* W1p  = fc1o + (size_t)NG * FH;              // S1*8
    short* W2p  = W1p + (size_t)S1 * 8;                // S2*8
    short* Wf1p = W2p + (size_t)S2 * 8;                // S3*8
    short* Wf2p = Wf1p + (size_t)S3 * 8;               // S4*8
    int*   deg  = (int*)(Wf2p + (size_t)S4 * 8);       // NN
    int*   cnt  = deg + NN;                            // NN
    int*   rowptr = cnt + NN;                          // NN+1
    int*   bsum = rowptr + NN + 1;                     // 128
    int*   eid  = bsum + 128;                          // NE
    float* Pmax = (float*)(eid + NE);                  // NT2*840
    float* Psum = Pmax + (size_t)NT2 * F2;             // NT2*840

    const int blk = 256;
    auto cdiv = [](long long a, long long b) { return (int)((a + b - 1) / b); };
    const int nb1024 = cdiv(NN, 1024);  // 98

    // ---- CSR critical path first: deg -> scan1 -> scan23 ----
    hipMemsetAsync(deg, 0, (size_t)NN * sizeof(int), stream);
    edge_deg<<<NB_FILL, blk, 0, stream>>>(dst, deg);
    scan_ph1<<<nb1024, 1024, 0, stream>>>(deg, rowptr, bsum);
    scan_ph23<<<nb1024, 1024, 0, stream>>>(rowptr, bsum, cnt, nb1024);

    // ---- edge_fill || cast_x || pack_all ----
    fill_cast_pack<<<NB_FILL + NB_CAST + NB_PACK, blk, 0, stream>>>(
        src, dst, rowptr, cnt, eid,
        x, Xb, W1, W1p, W2, W2p, Wf1, Wf1p, Wf2, Wf2p);

    // ---- conv1 (8 waves, CTW=1): h1 = bf16(relu((Xb+gather)@W1+b1)) ----
    conv_fused<1, true><<<NT2, 512, 0, stream>>>(
        Xb, rowptr, eid, W1p, b1, h1, F0, 96, 96);

    // ---- conv2 (8 waves x CTW=7) + per-tile partial pool ----
    conv2_part<<<NT2, 512, 0, stream>>>(h1, rowptr, eid, W2p, b2, h2, Pmax, Psum);

    // ---- pooling from partials + boundary rows ----
    pool_kernel<<<NG, blk, 0, stream>>>(h2, batch, Pmax, Psum, A3);

    // ---- fc head ----
    gemmN<2, true, true><<<cdiv(125LL * 32 * 64, blk), blk, 0, stream>>>(
        A3, Wf1p, bf1, fc1o, 1696, FH, FH, FH, 125, 32);
    gemmN<2, false, false><<<cdiv(125LL * 12 * 64, blk), blk, 0, stream>>>(
        fc1o, Wf2p, bf2, xg_out, 1024, FO, FO, FO, 125, 12);
}

// Round 12
// 344.874 us; speedup vs baseline: 1.0687x; 1.0687x over previous
//
#include <hip/hip_runtime.h>
#include <math.h>

#define NN 100000   // nodes
#define NE 400000   // edges
#define NG 2000     // graphs
#define F0 84       // num_features_xd
#define F2 840      // F0*10
#define FH 1024     // fc hidden
#define FO 384      // fc out
#define NT2 6250    // row tiles (NN/16)

typedef __attribute__((ext_vector_type(8))) short bf16x8;
typedef __attribute__((ext_vector_type(4))) float f32x4;

__device__ inline short f2bf(float f) {
    union { float f; unsigned u; } v; v.f = f;
    unsigned r = (v.u + 0x7FFFu + ((v.u >> 16) & 1u)) >> 16;
    return (short)r;
}
__device__ inline float b2f(short s) {
    union { unsigned u; float f; } v;
    v.u = ((unsigned)(unsigned short)s) << 16;
    return v.f;
}

// ---- pack geometry ----
#define S1 (8*3*64)
#define S2 (56*3*64)
#define S3 (64*53*64)
#define S4 (24*32*64)
#define PACK_TOT (S1 + S2 + S3 + S4)     // 278528
#define NB_DEG  1563                     // ceil(NE/256)
#define NB_CAST 4688                     // ceil(NN*12/256)
#define NB_PACK 1088                     // ceil(PACK_TOT/256)

__device__ inline void pack_one(const float* __restrict__ W, short* __restrict__ P,
                                int K, int N, int KB, int CT, int idx) {
    int lane = idx & 63;
    int t    = idx >> 6;
    int kb   = t % KB;
    int ct   = t / KB;
    int col  = ct * 16 + (lane & 15);
    int k0   = kb * 32 + ((lane >> 4) << 3);
    bf16x8 v;
#pragma unroll
    for (int j = 0; j < 8; ++j) {
        int k = k0 + j;
        float f = (k < K && col < N) ? W[(size_t)k * N + col] : 0.f;
        v[j] = f2bf(f);
    }
    *reinterpret_cast<bf16x8*>(P + (size_t)idx * 8) = v;
}

// ---- front: edge_deg || cast_x || pack_all in one launch ----
__global__ void front_kernel(const int* __restrict__ dst, int* __restrict__ deg,
                             const float* __restrict__ x, short* __restrict__ Xb,
                             const float* __restrict__ W1, short* __restrict__ P1,
                             const float* __restrict__ W2, short* __restrict__ P2,
                             const float* __restrict__ Wf1, short* __restrict__ P3,
                             const float* __restrict__ Wf2, short* __restrict__ P4) {
    int bid = blockIdx.x;
    if (bid < NB_DEG) {
        int e = bid * 256 + threadIdx.x;
        if (e < NE) atomicAdd(&deg[dst[e]], 1);
        return;
    }
    bid -= NB_DEG;
    if (bid < NB_CAST) {
        int idx = bid * 256 + threadIdx.x;
        if (idx < NN * 12) {
            int n = idx / 12;
            int c = idx - n * 12;
            int k0 = c * 8;
            bf16x8 v;
#pragma unroll
            for (int j = 0; j < 8; ++j) {
                int k = k0 + j;
                v[j] = (k < F0) ? f2bf(x[(size_t)n * F0 + k]) : (short)0;
            }
            *reinterpret_cast<bf16x8*>(Xb + (size_t)n * 96 + k0) = v;
        }
        return;
    }
    bid -= NB_CAST;
    int idx = bid * 256 + threadIdx.x;
    if (idx < S1) { pack_one(W1, P1, F0, F0, 3, 8, idx); return; }
    idx -= S1;
    if (idx < S2) { pack_one(W2, P2, F0, F2, 3, 56, idx); return; }
    idx -= S2;
    if (idx < S3) { pack_one(Wf1, P3, 1680, FH, 53, 64, idx); return; }
    idx -= S3;
    if (idx < S4) { pack_one(Wf2, P4, FH, FO, 32, 24, idx); return; }
}

// ---- scan phase 1 ----
__global__ void scan_ph1(const int* __restrict__ deg, int* __restrict__ rowptr,
                         int* __restrict__ bsum) {
    __shared__ int s[1024];
    int t = threadIdx.x;
    int i = blockIdx.x * 1024 + t;
    int v = (i < NN) ? deg[i] : 0;
    s[t] = v;
    __syncthreads();
    for (int d = 1; d < 1024; d <<= 1) {
        int u = (t >= d) ? s[t - d] : 0;
        __syncthreads();
        s[t] += u;
        __syncthreads();
    }
    if (i < NN) rowptr[i] = s[t] - v;
    if (t == 1023) bsum[blockIdx.x] = s[t];
}

// ---- scan phase 2+3 (also zeroes cnt for edge_fill) ----
__global__ void scan_ph23(int* __restrict__ rowptr, const int* __restrict__ bsum,
                          int* __restrict__ cnt, int nb) {
    __shared__ int s[128];
    int t = threadIdx.x;
    int b = blockIdx.x;
    if (t < 128) s[t] = (t < b && t < nb) ? bsum[t] : 0;
    __syncthreads();
    for (int d = 64; d >= 1; d >>= 1) {
        if (t < d) s[t] += s[t + d];
        __syncthreads();
    }
    int off = s[0];
    int i = b * 1024 + t;
    if (i < NN) {
        rowptr[i] += off;
        cnt[i] = 0;
    }
    if (i == 0) rowptr[NN] = NE;
}

__global__ void edge_fill(const int* __restrict__ src, const int* __restrict__ dst,
                          const int* __restrict__ rowptr, int* __restrict__ cnt,
                          int* __restrict__ eid) {
    int e = blockIdx.x * blockDim.x + threadIdx.x;
    if (e >= NE) return;
    int d = dst[e];
    int p = rowptr[d] + atomicAdd(&cnt[d], 1);
    eid[p] = src[e];
}

// ---- gather item (16B granularity, 2-way unrolled neighbor loop) ----
// item = (row r, 8-elem chunk c); writes 16B into fragment slot.
__device__ inline void gather_item(const short* __restrict__ H,
                                   const int* __restrict__ rowptr,
                                   const int* __restrict__ eid,
                                   int n, int r, int c, short* __restrict__ ldsTile) {
    int off = c * 8;
    bf16x8 sv = *reinterpret_cast<const bf16x8*>(H + (size_t)n * 96 + off);
    float acc[8];
#pragma unroll
    for (int j = 0; j < 8; ++j) acc[j] = b2f(sv[j]);
    int e0 = rowptr[n], e1 = rowptr[n + 1];
    int e = e0;
    for (; e + 1 < e1; e += 2) {
        int s0 = eid[e], s1 = eid[e + 1];
        bf16x8 v0 = *reinterpret_cast<const bf16x8*>(H + (size_t)s0 * 96 + off);
        bf16x8 v1 = *reinterpret_cast<const bf16x8*>(H + (size_t)s1 * 96 + off);
#pragma unroll
        for (int j = 0; j < 8; ++j) acc[j] += b2f(v0[j]) + b2f(v1[j]);
    }
    if (e < e1) {
        int s0 = eid[e];
        bf16x8 v0 = *reinterpret_cast<const bf16x8*>(H + (size_t)s0 * 96 + off);
#pragma unroll
        for (int j = 0; j < 8; ++j) acc[j] += b2f(v0[j]);
    }
    bf16x8 o;
#pragma unroll
    for (int j = 0; j < 8; ++j) o[j] = f2bf(acc[j]);
    int kb = c >> 2, q = c & 3;
    *reinterpret_cast<bf16x8*>(&ldsTile[kb * 512 + (q * 16 + r) * 8]) = o;
}

// ---- conv1 fused gather+gemm: 4 waves, one 16-row tile, CTW=2 (8 ct slots) --
template <int CTW, int NWAVES, bool OUTBF16>
__global__ void conv_fused(const short* __restrict__ H,
                           const int* __restrict__ rowptr,
                           const int* __restrict__ eid,
                           const short* __restrict__ Bp,
                           const float* __restrict__ bias,
                           void* __restrict__ Cout,
                           int Nbias, int ldc, int ncols) {
    __shared__ short Alds[3 * 512];
    int rt = blockIdx.x;
    int t  = threadIdx.x;

    for (int item = t; item < 192; item += NWAVES * 64) {
        int r = item / 12;
        int c = item - r * 12;
        gather_item(H, rowptr, eid, rt * 16 + r, r, c, Alds);
    }
    __syncthreads();

    int wave = t >> 6;
    int lane = t & 63;
    f32x4 acc[CTW];
#pragma unroll
    for (int u = 0; u < CTW; ++u) acc[u] = (f32x4){0.f, 0.f, 0.f, 0.f};
    const short* Bbase = Bp + (size_t)(wave * CTW) * 3 * 512 + lane * 8;
#pragma unroll
    for (int kb = 0; kb < 3; ++kb) {
        bf16x8 a = *reinterpret_cast<const bf16x8*>(&Alds[kb * 512 + lane * 8]);
#pragma unroll
        for (int u = 0; u < CTW; ++u) {
            bf16x8 b = *reinterpret_cast<const bf16x8*>(Bbase + ((size_t)u * 3 + kb) * 512);
            acc[u] = __builtin_amdgcn_mfma_f32_16x16x32_bf16(a, b, acc[u], 0, 0, 0);
        }
    }
    int row0 = rt * 16 + ((lane >> 4) << 2);
#pragma unroll
    for (int u = 0; u < CTW; ++u) {
        int col = (wave * CTW + u) * 16 + (lane & 15);
        float bi = (col < Nbias) ? bias[col] : 0.f;
        if (col < ncols) {
#pragma unroll
            for (int r = 0; r < 4; ++r) {
                float v = fmaxf(acc[u][r] + bi, 0.f);
                if (OUTBF16) ((short*)Cout)[(size_t)(row0 + r) * ldc + col] = f2bf(v);
                else         ((float*)Cout)[(size_t)(row0 + r) * ldc + col] = v;
            }
        }
    }
}

// ---- conv2: 8 waves x CTW=7 (512 threads), one 16-row tile, partial pool ----
__global__ __launch_bounds__(512) void conv2_part(
        const short* __restrict__ H, const int* __restrict__ rowptr,
        const int* __restrict__ eid, const short* __restrict__ Bp,
        const float* __restrict__ bias, float* __restrict__ h2,
        float* __restrict__ Pmax, float* __restrict__ Psum) {
    __shared__ short Alds[3 * 512];
    int rt = blockIdx.x;
    int t  = threadIdx.x;

    if (t < 192) {
        int r = t / 12;
        int c = t - r * 12;
        gather_item(H, rowptr, eid, rt * 16 + r, r, c, Alds);
    }
    __syncthreads();

    int wave = t >> 6;   // 0..7
    int lane = t & 63;
    f32x4 acc[7];
#pragma unroll
    for (int u = 0; u < 7; ++u) acc[u] = (f32x4){0.f, 0.f, 0.f, 0.f};
    const short* Bbase = Bp + (size_t)(wave * 7) * 3 * 512 + lane * 8;
#pragma unroll
    for (int kb = 0; kb < 3; ++kb) {
        bf16x8 a = *reinterpret_cast<const bf16x8*>(&Alds[kb * 512 + lane * 8]);
#pragma unroll
        for (int u = 0; u < 7; ++u) {
            bf16x8 b = *reinterpret_cast<const bf16x8*>(Bbase + ((size_t)u * 3 + kb) * 512);
            acc[u] = __builtin_amdgcn_mfma_f32_16x16x32_bf16(a, b, acc[u], 0, 0, 0);
        }
    }
    int row0 = rt * 16 + ((lane >> 4) << 2);
#pragma unroll
    for (int u = 0; u < 7; ++u) {
        int col = (wave * 7 + u) * 16 + (lane & 15);
        if (col < F2) {
            float bi = bias[col];
            float m = -INFINITY, sm = 0.f;
#pragma unroll
            for (int r = 0; r < 4; ++r) {
                float v = fmaxf(acc[u][r] + bi, 0.f);
                h2[(size_t)(row0 + r) * F2 + col] = v;
                m = fmaxf(m, v);
                sm += v;
            }
            m = fmaxf(m, __shfl_xor(m, 16));
            m = fmaxf(m, __shfl_xor(m, 32));
            sm += __shfl_xor(sm, 16);
            sm += __shfl_xor(sm, 32);
            if (lane < 16) {
                Pmax[(size_t)rt * F2 + col] = m;
                Psum[(size_t)rt * F2 + col] = sm;
            }
        }
    }
}

// ---- pool: per graph; full tiles from partials, boundary rows from h2 ----
__global__ void pool_kernel(const float* __restrict__ h2,
                            const int* __restrict__ batch,
                            const float* __restrict__ Pmax,
                            const float* __restrict__ Psum,
                            short* __restrict__ A3) {
    int g = blockIdx.x;
    int t = threadIdx.x;  // 256
    __shared__ int se[2];
    if (t < 2) {
        int target = g + t;
        int lo = 0, hi = NN;
        while (lo < hi) {
            int mid = (lo + hi) >> 1;
            if (batch[mid] < target) lo = mid + 1; else hi = mid;
        }
        se[t] = lo;
    }
    __syncthreads();
    int s = se[0], e = se[1];
    int t0 = (s + 15) >> 4;   // first full tile
    int t1 = e >> 4;          // end of full tiles
    if (t < 210) {
        int c4 = t * 4;
        float sm0 = 0.f, sm1 = 0.f, sm2 = 0.f, sm3 = 0.f;
        float mx0 = -INFINITY, mx1 = -INFINITY, mx2 = -INFINITY, mx3 = -INFINITY;
        if (t1 >= t0) {
            for (int tile = t0; tile < t1; ++tile) {
                float4 pm = *reinterpret_cast<const float4*>(Pmax + (size_t)tile * F2 + c4);
                float4 ps = *reinterpret_cast<const float4*>(Psum + (size_t)tile * F2 + c4);
                mx0 = fmaxf(mx0, pm.x); mx1 = fmaxf(mx1, pm.y);
                mx2 = fmaxf(mx2, pm.z); mx3 = fmaxf(mx3, pm.w);
                sm0 += ps.x; sm1 += ps.y; sm2 += ps.z; sm3 += ps.w;
            }
            for (int n = s; n < (t0 << 4); ++n) {
                float4 v = *reinterpret_cast<const float4*>(h2 + (size_t)n * F2 + c4);
                sm0 += v.x; sm1 += v.y; sm2 += v.z; sm3 += v.w;
                mx0 = fmaxf(mx0, v.x); mx1 = fmaxf(mx1, v.y);
                mx2 = fmaxf(mx2, v.z); mx3 = fmaxf(mx3, v.w);
            }
            for (int n = (t1 << 4); n < e; ++n) {
                float4 v = *reinterpret_cast<const float4*>(h2 + (size_t)n * F2 + c4);
                sm0 += v.x; sm1 += v.y; sm2 += v.z; sm3 += v.w;
                mx0 = fmaxf(mx0, v.x); mx1 = fmaxf(mx1, v.y);
                mx2 = fmaxf(mx2, v.z); mx3 = fmaxf(mx3, v.w);
            }
        } else {
            for (int n = s; n < e; ++n) {
                float4 v = *reinterpret_cast<const float4*>(h2 + (size_t)n * F2 + c4);
                sm0 += v.x; sm1 += v.y; sm2 += v.z; sm3 += v.w;
                mx0 = fmaxf(mx0, v.x); mx1 = fmaxf(mx1, v.y);
                mx2 = fmaxf(mx2, v.z); mx3 = fmaxf(mx3, v.w);
            }
        }
        short* xr = A3 + (size_t)g * 1696;
        short4 mo, so;
        mo.x = f2bf(mx0); mo.y = f2bf(mx1); mo.z = f2bf(mx2); mo.w = f2bf(mx3);
        so.x = f2bf(sm0); so.y = f2bf(sm1); so.z = f2bf(sm2); so.w = f2bf(sm3);
        *reinterpret_cast<short4*>(xr + c4)      = mo;
        *reinterpret_cast<short4*>(xr + F2 + c4) = so;
    }
    if (t >= 210 && t < 214) {
        short4 z = {0, 0, 0, 0};
        *reinterpret_cast<short4*>(A3 + (size_t)g * 1696 + 1680 + (t - 210) * 4) = z;
    }
}

// ---- plain MFMA GEMM (fc head) ----
template <int CTW, bool RELU, bool OUTBF16>
__global__ void gemmN(const short* __restrict__ A, const short* __restrict__ Bp,
                      const float* __restrict__ bias, void* __restrict__ Cout,
                      int Kp, int Nbias, int ldc, int ncols,
                      int rowTiles, int ctGroups) {
    int gid = blockIdx.x * blockDim.x + threadIdx.x;
    int w   = gid >> 6;
    if (w >= rowTiles * ctGroups) return;
    int lane = gid & 63;
    int rt = w / ctGroups;
    int cg = w - rt * ctGroups;
    int KB = Kp >> 5;
    const short* Ap = A + (size_t)(rt * 16 + (lane & 15)) * Kp + ((lane >> 4) << 3);
    const short* Bbase = Bp + (size_t)(cg * CTW) * KB * 512 + lane * 8;
    f32x4 acc[CTW];
#pragma unroll
    for (int u = 0; u < CTW; ++u) acc[u] = (f32x4){0.f, 0.f, 0.f, 0.f};
    for (int kb = 0; kb < KB; ++kb) {
        bf16x8 a = *reinterpret_cast<const bf16x8*>(Ap + kb * 32);
#pragma unroll
        for (int u = 0; u < CTW; ++u) {
            bf16x8 b = *reinterpret_cast<const bf16x8*>(Bbase + ((size_t)u * KB + kb) * 512);
            acc[u] = __builtin_amdgcn_mfma_f32_16x16x32_bf16(a, b, acc[u], 0, 0, 0);
        }
    }
    int row0 = rt * 16 + ((lane >> 4) << 2);
#pragma unroll
    for (int u = 0; u < CTW; ++u) {
        int col = (cg * CTW + u) * 16 + (lane & 15);
        float bi = (col < Nbias) ? bias[col] : 0.f;
        if (col < ncols) {
#pragma unroll
            for (int r = 0; r < 4; ++r) {
                int row = row0 + r;
                float v = acc[u][r] + bi;
                if (RELU) v = fmaxf(v, 0.f);
                if (OUTBF16) ((short*)Cout)[(size_t)row * ldc + col] = f2bf(v);
                else         ((float*)Cout)[(size_t)row * ldc + col] = v;
            }
        }
    }
}

extern "C" void kernel_launch(void* const* d_in, const int* in_sizes, int n_in,
                              void* d_out, int out_size, void* d_ws, size_t ws_size,
                              hipStream_t stream) {
    const float* x    = (const float*)d_in[0];
    const int*   ei   = (const int*)d_in[1];
    const int*   batch= (const int*)d_in[2];
    const float* W1   = (const float*)d_in[3];
    const float* b1   = (const float*)d_in[4];
    const float* W2   = (const float*)d_in[5];
    const float* b2   = (const float*)d_in[6];
    const float* Wf1  = (const float*)d_in[7];
    const float* bf1  = (const float*)d_in[8];
    const float* Wf2  = (const float*)d_in[9];
    const float* bf2  = (const float*)d_in[10];

    const int* src = ei;
    const int* dst = ei + NE;

    float* xg_out = (float*)d_out;                    // [NG, FO]
    float* h2     = (float*)d_out + (size_t)NG * FO;  // [NN, F2] fp32

    // workspace layout
    short* Xb   = (short*)d_ws;                        // NN*96
    short* h1   = Xb + (size_t)NN * 96;                // NN*96
    short* A3   = h1 + (size_t)NN * 96;                // NG*1696
    short* fc1o = A3 + (size_t)NG * 1696;              // NG*1024
    short* W1p  = fc1o + (size_t)NG * FH;              // S1*8
    short* W2p  = W1p + (size_t)S1 * 8;                // S2*8
    short* Wf1p = W2p + (size_t)S2 * 8;                // S3*8
    short* Wf2p = Wf1p + (size_t)S3 * 8;               // S4*8
    int*   deg  = (int*)(Wf2p + (size_t)S4 * 8);       // NN
    int*   cnt  = deg + NN;                            // NN
    int*   rowptr = cnt + NN;                          // NN+1
    int*   bsum = rowptr + NN + 1;                     // 128
    int*   eid  = bsum + 128;                          // NE
    float* Pmax = (float*)(eid + NE);                  // NT2*840
    float* Psum = Pmax + (size_t)NT2 * F2;             // NT2*840

    const int blk = 256;
    auto cdiv = [](long long a, long long b) { return (int)((a + b - 1) / b); };
    const int nb1024 = cdiv(NN, 1024);  // 98

    // ---- front: zero deg, then deg || cast_x || pack_all ----
    hipMemsetAsync(deg, 0, (size_t)NN * sizeof(int), stream);
    front_kernel<<<NB_DEG + NB_CAST + NB_PACK, blk, 0, stream>>>(
        dst, deg, x, Xb, W1, W1p, W2, W2p, Wf1, Wf1p, Wf2, Wf2p);

    // ---- CSR scan + fill ----
    scan_ph1<<<nb1024, 1024, 0, stream>>>(deg, rowptr, bsum);
    scan_ph23<<<nb1024, 1024, 0, stream>>>(rowptr, bsum, cnt, nb1024);
    edge_fill<<<cdiv(NE, blk), blk, 0, stream>>>(src, dst, rowptr, cnt, eid);

    // ---- conv1 (fused gather+gemm, 4 waves): h1 = bf16(relu((Xb+gather)@W1+b1)) ----
    conv_fused<2, 4, true><<<NT2, 256, 0, stream>>>(
        Xb, rowptr, eid, W1p, b1, h1, F0, 96, 96);

    // ---- conv2 (8 waves x CTW=7) + per-tile partial pool ----
    conv2_part<<<NT2, 512, 0, stream>>>(h1, rowptr, eid, W2p, b2, h2, Pmax, Psum);

    // ---- pooling from partials + boundary rows ----
    pool_kernel<<<NG, blk, 0, stream>>>(h2, batch, Pmax, Psum, A3);

    // ---- fc head ----
    gemmN<2, true, true><<<cdiv(125LL * 32 * 64, blk), blk, 0, stream>>>(
        A3, Wf1p, bf1, fc1o, 1696, FH, FH, FH, 125, 32);
    gemmN<2, false, false><<<cdiv(125LL * 12 * 64, blk), blk, 0, stream>>>(
        fc1o, Wf2p, bf2, xg_out, 1024, FO, FO, FO, 125, 12);
}

// Round 13
// 338.511 us; speedup vs baseline: 1.0888x; 1.0188x over previous
//
#include <hip/hip_runtime.h>
#include <math.h>

#define NN 100000   // nodes
#define NE 400000   // edges
#define NG 2000     // graphs
#define F0 84       // num_features_xd
#define F2 840      // F0*10
#define FH 1024     // fc hidden
#define FO 384      // fc out
#define NT2 6250    // row tiles (NN/16)

typedef __attribute__((ext_vector_type(8))) short bf16x8;
typedef __attribute__((ext_vector_type(4))) float f32x4;

__device__ inline short f2bf(float f) {
    union { float f; unsigned u; } v; v.f = f;
    unsigned r = (v.u + 0x7FFFu + ((v.u >> 16) & 1u)) >> 16;
    return (short)r;
}
__device__ inline float b2f(short s) {
    union { unsigned u; float f; } v;
    v.u = ((unsigned)(unsigned short)s) << 16;
    return v.f;
}

// ---- pack geometry ----
#define S1 (8*3*64)
#define S2 (56*3*64)
#define S3 (64*53*64)
#define S4 (24*32*64)
#define PACK_TOT (S1 + S2 + S3 + S4)     // 278528
#define NB_DEG  1563                     // ceil(NE/256)
#define NB_CAST 4688                     // ceil(NN*12/256)
#define NB_PACK 1088                     // ceil(PACK_TOT/256)

__device__ inline void pack_one(const float* __restrict__ W, short* __restrict__ P,
                                int K, int N, int KB, int CT, int idx) {
    int lane = idx & 63;
    int t    = idx >> 6;
    int kb   = t % KB;
    int ct   = t / KB;
    int col  = ct * 16 + (lane & 15);
    int k0   = kb * 32 + ((lane >> 4) << 3);
    bf16x8 v;
#pragma unroll
    for (int j = 0; j < 8; ++j) {
        int k = k0 + j;
        float f = (k < K && col < N) ? W[(size_t)k * N + col] : 0.f;
        v[j] = f2bf(f);
    }
    *reinterpret_cast<bf16x8*>(P + (size_t)idx * 8) = v;
}

// ---- front: edge_deg || cast_x || pack_all in one launch ----
__global__ void front_kernel(const int* __restrict__ dst, int* __restrict__ deg,
                             const float* __restrict__ x, short* __restrict__ Xb,
                             const float* __restrict__ W1, short* __restrict__ P1,
                             const float* __restrict__ W2, short* __restrict__ P2,
                             const float* __restrict__ Wf1, short* __restrict__ P3,
                             const float* __restrict__ Wf2, short* __restrict__ P4) {
    int bid = blockIdx.x;
    if (bid < NB_DEG) {
        int e = bid * 256 + threadIdx.x;
        if (e < NE) atomicAdd(&deg[dst[e]], 1);
        return;
    }
    bid -= NB_DEG;
    if (bid < NB_CAST) {
        int idx = bid * 256 + threadIdx.x;
        if (idx < NN * 12) {
            int n = idx / 12;
            int c = idx - n * 12;
            int k0 = c * 8;
            bf16x8 v;
#pragma unroll
            for (int j = 0; j < 8; ++j) {
                int k = k0 + j;
                v[j] = (k < F0) ? f2bf(x[(size_t)n * F0 + k]) : (short)0;
            }
            *reinterpret_cast<bf16x8*>(Xb + (size_t)n * 96 + k0) = v;
        }
        return;
    }
    bid -= NB_CAST;
    int idx = bid * 256 + threadIdx.x;
    if (idx < S1) { pack_one(W1, P1, F0, F0, 3, 8, idx); return; }
    idx -= S1;
    if (idx < S2) { pack_one(W2, P2, F0, F2, 3, 56, idx); return; }
    idx -= S2;
    if (idx < S3) { pack_one(Wf1, P3, 1680, FH, 53, 64, idx); return; }
    idx -= S3;
    if (idx < S4) { pack_one(Wf2, P4, FH, FO, 32, 24, idx); return; }
}

// ---- scan phase 1 ----
__global__ void scan_ph1(const int* __restrict__ deg, int* __restrict__ rowptr,
                         int* __restrict__ bsum) {
    __shared__ int s[1024];
    int t = threadIdx.x;
    int i = blockIdx.x * 1024 + t;
    int v = (i < NN) ? deg[i] : 0;
    s[t] = v;
    __syncthreads();
    for (int d = 1; d < 1024; d <<= 1) {
        int u = (t >= d) ? s[t - d] : 0;
        __syncthreads();
        s[t] += u;
        __syncthreads();
    }
    if (i < NN) rowptr[i] = s[t] - v;
    if (t == 1023) bsum[blockIdx.x] = s[t];
}

// ---- scan phase 2+3 (also zeroes cnt for edge_fill) ----
__global__ void scan_ph23(int* __restrict__ rowptr, const int* __restrict__ bsum,
                          int* __restrict__ cnt, int nb) {
    __shared__ int s[128];
    int t = threadIdx.x;
    int b = blockIdx.x;
    if (t < 128) s[t] = (t < b && t < nb) ? bsum[t] : 0;
    __syncthreads();
    for (int d = 64; d >= 1; d >>= 1) {
        if (t < d) s[t] += s[t + d];
        __syncthreads();
    }
    int off = s[0];
    int i = b * 1024 + t;
    if (i < NN) {
        rowptr[i] += off;
        cnt[i] = 0;
    }
    if (i == 0) rowptr[NN] = NE;
}

__global__ void edge_fill(const int* __restrict__ src, const int* __restrict__ dst,
                          const int* __restrict__ rowptr, int* __restrict__ cnt,
                          int* __restrict__ eid) {
    int e = blockIdx.x * blockDim.x + threadIdx.x;
    if (e >= NE) return;
    int d = dst[e];
    int p = rowptr[d] + atomicAdd(&cnt[d], 1);
    eid[p] = src[e];
}

// ---- gather item (16B granularity, 2-way unrolled neighbor loop) ----
__device__ inline void gather_item(const short* __restrict__ H,
                                   const int* __restrict__ rowptr,
                                   const int* __restrict__ eid,
                                   int n, int r, int c, short* __restrict__ ldsTile) {
    int off = c * 8;
    bf16x8 sv = *reinterpret_cast<const bf16x8*>(H + (size_t)n * 96 + off);
    float acc[8];
#pragma unroll
    for (int j = 0; j < 8; ++j) acc[j] = b2f(sv[j]);
    int e0 = rowptr[n], e1 = rowptr[n + 1];
    int e = e0;
    for (; e + 1 < e1; e += 2) {
        int s0 = eid[e], s1 = eid[e + 1];
        bf16x8 v0 = *reinterpret_cast<const bf16x8*>(H + (size_t)s0 * 96 + off);
        bf16x8 v1 = *reinterpret_cast<const bf16x8*>(H + (size_t)s1 * 96 + off);
#pragma unroll
        for (int j = 0; j < 8; ++j) acc[j] += b2f(v0[j]) + b2f(v1[j]);
    }
    if (e < e1) {
        int s0 = eid[e];
        bf16x8 v0 = *reinterpret_cast<const bf16x8*>(H + (size_t)s0 * 96 + off);
#pragma unroll
        for (int j = 0; j < 8; ++j) acc[j] += b2f(v0[j]);
    }
    bf16x8 o;
#pragma unroll
    for (int j = 0; j < 8; ++j) o[j] = f2bf(acc[j]);
    int kb = c >> 2, q = c & 3;
    *reinterpret_cast<bf16x8*>(&ldsTile[kb * 512 + (q * 16 + r) * 8]) = o;
}

// ---- conv1 fused gather+gemm: 4 waves, one 16-row tile, CTW=2 (8 ct slots) --
template <int CTW, int NWAVES, bool OUTBF16>
__global__ void conv_fused(const short* __restrict__ H,
                           const int* __restrict__ rowptr,
                           const int* __restrict__ eid,
                           const short* __restrict__ Bp,
                           const float* __restrict__ bias,
                           void* __restrict__ Cout,
                           int Nbias, int ldc, int ncols) {
    __shared__ short Alds[3 * 512];
    int rt = blockIdx.x;
    int t  = threadIdx.x;

    for (int item = t; item < 192; item += NWAVES * 64) {
        int r = item / 12;
        int c = item - r * 12;
        gather_item(H, rowptr, eid, rt * 16 + r, r, c, Alds);
    }
    __syncthreads();

    int wave = t >> 6;
    int lane = t & 63;
    f32x4 acc[CTW];
#pragma unroll
    for (int u = 0; u < CTW; ++u) acc[u] = (f32x4){0.f, 0.f, 0.f, 0.f};
    const short* Bbase = Bp + (size_t)(wave * CTW) * 3 * 512 + lane * 8;
#pragma unroll
    for (int kb = 0; kb < 3; ++kb) {
        bf16x8 a = *reinterpret_cast<const bf16x8*>(&Alds[kb * 512 + lane * 8]);
#pragma unroll
        for (int u = 0; u < CTW; ++u) {
            bf16x8 b = *reinterpret_cast<const bf16x8*>(Bbase + ((size_t)u * 3 + kb) * 512);
            acc[u] = __builtin_amdgcn_mfma_f32_16x16x32_bf16(a, b, acc[u], 0, 0, 0);
        }
    }
    int row0 = rt * 16 + ((lane >> 4) << 2);
#pragma unroll
    for (int u = 0; u < CTW; ++u) {
        int col = (wave * CTW + u) * 16 + (lane & 15);
        float bi = (col < Nbias) ? bias[col] : 0.f;
        if (col < ncols) {
#pragma unroll
            for (int r = 0; r < 4; ++r) {
                float v = fmaxf(acc[u][r] + bi, 0.f);
                if (OUTBF16) ((short*)Cout)[(size_t)(row0 + r) * ldc + col] = f2bf(v);
                else         ((float*)Cout)[(size_t)(row0 + r) * ldc + col] = v;
            }
        }
    }
}

// ---- conv2: 8 waves x CTW=7, TWO 16-row tiles per block (B reused 2x) ----
__global__ __launch_bounds__(512, 4) void conv2_part(
        const short* __restrict__ H, const int* __restrict__ rowptr,
        const int* __restrict__ eid, const short* __restrict__ Bp,
        const float* __restrict__ bias, float* __restrict__ h2,
        float* __restrict__ Pmax, float* __restrict__ Psum) {
    __shared__ short Alds[2][3 * 512];
    int bb = blockIdx.x;      // 0..3124, covers rows bb*32 .. bb*32+31
    int t  = threadIdx.x;
    int base = bb * 32;

    if (t < 384) {
        int tile = t >= 192;
        int it   = t - (tile ? 192 : 0);
        int r = it / 12;
        int c = it - r * 12;
        gather_item(H, rowptr, eid, base + tile * 16 + r, r, c, Alds[tile]);
    }
    __syncthreads();

    int wave = t >> 6;   // 0..7
    int lane = t & 63;
    f32x4 acc0[7], acc1[7];
#pragma unroll
    for (int u = 0; u < 7; ++u) {
        acc0[u] = (f32x4){0.f, 0.f, 0.f, 0.f};
        acc1[u] = (f32x4){0.f, 0.f, 0.f, 0.f};
    }
    const short* Bbase = Bp + (size_t)(wave * 7) * 3 * 512 + lane * 8;
#pragma unroll
    for (int kb = 0; kb < 3; ++kb) {
        bf16x8 a0 = *reinterpret_cast<const bf16x8*>(&Alds[0][kb * 512 + lane * 8]);
        bf16x8 a1 = *reinterpret_cast<const bf16x8*>(&Alds[1][kb * 512 + lane * 8]);
#pragma unroll
        for (int u = 0; u < 7; ++u) {
            bf16x8 b = *reinterpret_cast<const bf16x8*>(Bbase + ((size_t)u * 3 + kb) * 512);
            acc0[u] = __builtin_amdgcn_mfma_f32_16x16x32_bf16(a0, b, acc0[u], 0, 0, 0);
            acc1[u] = __builtin_amdgcn_mfma_f32_16x16x32_bf16(a1, b, acc1[u], 0, 0, 0);
        }
    }
    int rg = (lane >> 4) << 2;
    int colb = wave * 7 * 16 + (lane & 15);
    // ---- tile 0 epilogue ----
#pragma unroll
    for (int u = 0; u < 7; ++u) {
        int col = colb + u * 16;
        if (col < F2) {
            float bi = bias[col];
            float m = -INFINITY, sm = 0.f;
            int row0 = base + rg;
#pragma unroll
            for (int r = 0; r < 4; ++r) {
                float v = fmaxf(acc0[u][r] + bi, 0.f);
                h2[(size_t)(row0 + r) * F2 + col] = v;
                m = fmaxf(m, v);
                sm += v;
            }
            m = fmaxf(m, __shfl_xor(m, 16));
            m = fmaxf(m, __shfl_xor(m, 32));
            sm += __shfl_xor(sm, 16);
            sm += __shfl_xor(sm, 32);
            if (lane < 16) {
                Pmax[(size_t)(bb * 2) * F2 + col] = m;
                Psum[(size_t)(bb * 2) * F2 + col] = sm;
            }
        }
    }
    // ---- tile 1 epilogue ----
#pragma unroll
    for (int u = 0; u < 7; ++u) {
        int col = colb + u * 16;
        if (col < F2) {
            float bi = bias[col];
            float m = -INFINITY, sm = 0.f;
            int row0 = base + 16 + rg;
#pragma unroll
            for (int r = 0; r < 4; ++r) {
                float v = fmaxf(acc1[u][r] + bi, 0.f);
                h2[(size_t)(row0 + r) * F2 + col] = v;
                m = fmaxf(m, v);
                sm += v;
            }
            m = fmaxf(m, __shfl_xor(m, 16));
            m = fmaxf(m, __shfl_xor(m, 32));
            sm += __shfl_xor(sm, 16);
            sm += __shfl_xor(sm, 32);
            if (lane < 16) {
                Pmax[(size_t)(bb * 2 + 1) * F2 + col] = m;
                Psum[(size_t)(bb * 2 + 1) * F2 + col] = sm;
            }
        }
    }
}

// ---- pool: per graph; full tiles from partials, boundary rows from h2 ----
__global__ void pool_kernel(const float* __restrict__ h2,
                            const int* __restrict__ batch,
                            const float* __restrict__ Pmax,
                            const float* __restrict__ Psum,
                            short* __restrict__ A3) {
    int g = blockIdx.x;
    int t = threadIdx.x;  // 256
    __shared__ int se[2];
    if (t < 2) {
        int target = g + t;
        int lo = 0, hi = NN;
        while (lo < hi) {
            int mid = (lo + hi) >> 1;
            if (batch[mid] < target) lo = mid + 1; else hi = mid;
        }
        se[t] = lo;
    }
    __syncthreads();
    int s = se[0], e = se[1];
    int t0 = (s + 15) >> 4;   // first full tile
    int t1 = e >> 4;          // end of full tiles
    if (t < 210) {
        int c4 = t * 4;
        float sm0 = 0.f, sm1 = 0.f, sm2 = 0.f, sm3 = 0.f;
        float mx0 = -INFINITY, mx1 = -INFINITY, mx2 = -INFINITY, mx3 = -INFINITY;
        if (t1 >= t0) {
            for (int tile = t0; tile < t1; ++tile) {
                float4 pm = *reinterpret_cast<const float4*>(Pmax + (size_t)tile * F2 + c4);
                float4 ps = *reinterpret_cast<const float4*>(Psum + (size_t)tile * F2 + c4);
                mx0 = fmaxf(mx0, pm.x); mx1 = fmaxf(mx1, pm.y);
                mx2 = fmaxf(mx2, pm.z); mx3 = fmaxf(mx3, pm.w);
                sm0 += ps.x; sm1 += ps.y; sm2 += ps.z; sm3 += ps.w;
            }
            for (int n = s; n < (t0 << 4); ++n) {
                float4 v = *reinterpret_cast<const float4*>(h2 + (size_t)n * F2 + c4);
                sm0 += v.x; sm1 += v.y; sm2 += v.z; sm3 += v.w;
                mx0 = fmaxf(mx0, v.x); mx1 = fmaxf(mx1, v.y);
                mx2 = fmaxf(mx2, v.z); mx3 = fmaxf(mx3, v.w);
            }
            for (int n = (t1 << 4); n < e; ++n) {
                float4 v = *reinterpret_cast<const float4*>(h2 + (size_t)n * F2 + c4);
                sm0 += v.x; sm1 += v.y; sm2 += v.z; sm3 += v.w;
                mx0 = fmaxf(mx0, v.x); mx1 = fmaxf(mx1, v.y);
                mx2 = fmaxf(mx2, v.z); mx3 = fmaxf(mx3, v.w);
            }
        } else {
            for (int n = s; n < e; ++n) {
                float4 v = *reinterpret_cast<const float4*>(h2 + (size_t)n * F2 + c4);
                sm0 += v.x; sm1 += v.y; sm2 += v.z; sm3 += v.w;
                mx0 = fmaxf(mx0, v.x); mx1 = fmaxf(mx1, v.y);
                mx2 = fmaxf(mx2, v.z); mx3 = fmaxf(mx3, v.w);
            }
        }
        short* xr = A3 + (size_t)g * 1696;
        short4 mo, so;
        mo.x = f2bf(mx0); mo.y = f2bf(mx1); mo.z = f2bf(mx2); mo.w = f2bf(mx3);
        so.x = f2bf(sm0); so.y = f2bf(sm1); so.z = f2bf(sm2); so.w = f2bf(sm3);
        *reinterpret_cast<short4*>(xr + c4)      = mo;
        *reinterpret_cast<short4*>(xr + F2 + c4) = so;
    }
    if (t >= 210 && t < 214) {
        short4 z = {0, 0, 0, 0};
        *reinterpret_cast<short4*>(A3 + (size_t)g * 1696 + 1680 + (t - 210) * 4) = z;
    }
}

// ---- plain MFMA GEMM (fc head) ----
template <int CTW, bool RELU, bool OUTBF16>
__global__ void gemmN(const short* __restrict__ A, const short* __restrict__ Bp,
                      const float* __restrict__ bias, void* __restrict__ Cout,
                      int Kp, int Nbias, int ldc, int ncols,
                      int rowTiles, int ctGroups) {
    int gid = blockIdx.x * blockDim.x + threadIdx.x;
    int w   = gid >> 6;
    if (w >= rowTiles * ctGroups) return;
    int lane = gid & 63;
    int rt = w / ctGroups;
    int cg = w - rt * ctGroups;
    int KB = Kp >> 5;
    const short* Ap = A + (size_t)(rt * 16 + (lane & 15)) * Kp + ((lane >> 4) << 3);
    const short* Bbase = Bp + (size_t)(cg * CTW) * KB * 512 + lane * 8;
    f32x4 acc[CTW];
#pragma unroll
    for (int u = 0; u < CTW; ++u) acc[u] = (f32x4){0.f, 0.f, 0.f, 0.f};
    for (int kb = 0; kb < KB; ++kb) {
        bf16x8 a = *reinterpret_cast<const bf16x8*>(Ap + kb * 32);
#pragma unroll
        for (int u = 0; u < CTW; ++u) {
            bf16x8 b = *reinterpret_cast<const bf16x8*>(Bbase + ((size_t)u * KB + kb) * 512);
            acc[u] = __builtin_amdgcn_mfma_f32_16x16x32_bf16(a, b, acc[u], 0, 0, 0);
        }
    }
    int row0 = rt * 16 + ((lane >> 4) << 2);
#pragma unroll
    for (int u = 0; u < CTW; ++u) {
        int col = (cg * CTW + u) * 16 + (lane & 15);
        float bi = (col < Nbias) ? bias[col] : 0.f;
        if (col < ncols) {
#pragma unroll
            for (int r = 0; r < 4; ++r) {
                int row = row0 + r;
                float v = acc[u][r] + bi;
                if (RELU) v = fmaxf(v, 0.f);
                if (OUTBF16) ((short*)Cout)[(size_t)row * ldc + col] = f2bf(v);
                else         ((float*)Cout)[(size_t)row * ldc + col] = v;
            }
        }
    }
}

extern "C" void kernel_launch(void* const* d_in, const int* in_sizes, int n_in,
                              void* d_out, int out_size, void* d_ws, size_t ws_size,
                              hipStream_t stream) {
    const float* x    = (const float*)d_in[0];
    const int*   ei   = (const int*)d_in[1];
    const int*   batch= (const int*)d_in[2];
    const float* W1   = (const float*)d_in[3];
    const float* b1   = (const float*)d_in[4];
    const float* W2   = (const float*)d_in[5];
    const float* b2   = (const float*)d_in[6];
    const float* Wf1  = (const float*)d_in[7];
    const float* bf1  = (const float*)d_in[8];
    const float* Wf2  = (const float*)d_in[9];
    const float* bf2  = (const float*)d_in[10];

    const int* src = ei;
    const int* dst = ei + NE;

    float* xg_out = (float*)d_out;                    // [NG, FO]
    float* h2     = (float*)d_out + (size_t)NG * FO;  // [NN, F2] fp32

    // workspace layout
    short* Xb   = (short*)d_ws;                        // NN*96
    short* h1   = Xb + (size_t)NN * 96;                // NN*96
    short* A3   = h1 + (size_t)NN * 96;                // NG*1696
    short* fc1o = A3 + (size_t)NG * 1696;              // NG*1024
    short* W1p  = fc1o + (size_t)NG * FH;              // S1*8
    short* W2p  = W1p + (size_t)S1 * 8;                // S2*8
    short* Wf1p = W2p + (size_t)S2 * 8;                // S3*8
    short* Wf2p = Wf1p + (size_t)S3 * 8;               // S4*8
    int*   deg  = (int*)(Wf2p + (size_t)S4 * 8);       // NN
    int*   cnt  = deg + NN;                            // NN
    int*   rowptr = cnt + NN;                          // NN+1
    int*   bsum = rowptr + NN + 1;                     // 128
    int*   eid  = bsum + 128;                          // NE
    float* Pmax = (float*)(eid + NE);                  // NT2*840
    float* Psum = Pmax + (size_t)NT2 * F2;             // NT2*840

    const int blk = 256;
    auto cdiv = [](long long a, long long b) { return (int)((a + b - 1) / b); };
    const int nb1024 = cdiv(NN, 1024);  // 98

    // ---- front: zero deg, then deg || cast_x || pack_all ----
    hipMemsetAsync(deg, 0, (size_t)NN * sizeof(int), stream);
    front_kernel<<<NB_DEG + NB_CAST + NB_PACK, blk, 0, stream>>>(
        dst, deg, x, Xb, W1, W1p, W2, W2p, Wf1, Wf1p, Wf2, Wf2p);

    // ---- CSR scan + fill ----
    scan_ph1<<<nb1024, 1024, 0, stream>>>(deg, rowptr, bsum);
    scan_ph23<<<nb1024, 1024, 0, stream>>>(rowptr, bsum, cnt, nb1024);
    edge_fill<<<cdiv(NE, blk), blk, 0, stream>>>(src, dst, rowptr, cnt, eid);

    // ---- conv1 (fused gather+gemm, 4 waves): h1 = bf16(relu((Xb+gather)@W1+b1)) ----
    conv_fused<2, 4, true><<<NT2, 256, 0, stream>>>(
        Xb, rowptr, eid, W1p, b1, h1, F0, 96, 96);

    // ---- conv2 (8 waves x CTW=7, 2 row-tiles/block) + per-tile partial pool ----
    conv2_part<<<NT2 / 2, 512, 0, stream>>>(h1, rowptr, eid, W2p, b2, h2, Pmax, Psum);

    // ---- pooling from partials + boundary rows ----
    pool_kernel<<<NG, blk, 0, stream>>>(h2, batch, Pmax, Psum, A3);

    // ---- fc head ----
    gemmN<2, true, true><<<cdiv(125LL * 32 * 64, blk), blk, 0, stream>>>(
        A3, Wf1p, bf1, fc1o, 1696, FH, FH, FH, 125, 32);
    gemmN<2, false, false><<<cdiv(125LL * 12 * 64, blk), blk, 0, stream>>>(
        fc1o, Wf2p, bf2, xg_out, 1024, FO, FO, FO, 125, 12);
}

// Round 15
// 337.353 us; speedup vs baseline: 1.0926x; 1.0034x over previous
//
#include <hip/hip_runtime.h>
#include <math.h>

#define NN 100000   // nodes
#define NE 400000   // edges
#define NG 2000     // graphs
#define F0 84       // num_features_xd
#define F2 840      // F0*10
#define FH 1024     // fc hidden
#define FO 384      // fc out
#define NT2 6250    // row tiles (NN/16)

typedef __attribute__((ext_vector_type(8))) short bf16x8;
typedef __attribute__((ext_vector_type(4))) float f32x4;

__device__ inline short f2bf(float f) {
    union { float f; unsigned u; } v; v.f = f;
    unsigned r = (v.u + 0x7FFFu + ((v.u >> 16) & 1u)) >> 16;
    return (short)r;
}
__device__ inline float b2f(short s) {
    union { unsigned u; float f; } v;
    v.u = ((unsigned)(unsigned short)s) << 16;
    return v.f;
}

// ---- pack geometry ----
#define S1 (8*3*64)
#define S2 (56*3*64)
#define S3 (64*53*64)
#define S4 (24*32*64)
#define PACK_TOT (S1 + S2 + S3 + S4)     // 278528
#define NB_DEG  1563                     // ceil(NE/256)
#define NB_PACK 1088                     // ceil(PACK_TOT/256)

__device__ inline void pack_one(const float* __restrict__ W, short* __restrict__ P,
                                int K, int N, int KB, int CT, int idx) {
    int lane = idx & 63;
    int t    = idx >> 6;
    int kb   = t % KB;
    int ct   = t / KB;
    int col  = ct * 16 + (lane & 15);
    int k0   = kb * 32 + ((lane >> 4) << 3);
    bf16x8 v;
#pragma unroll
    for (int j = 0; j < 8; ++j) {
        int k = k0 + j;
        float f = (k < K && col < N) ? W[(size_t)k * N + col] : 0.f;
        v[j] = f2bf(f);
    }
    *reinterpret_cast<bf16x8*>(P + (size_t)idx * 8) = v;
}

// ---- front: edge_deg || pack_all ----
__global__ void front_kernel(const int* __restrict__ dst, int* __restrict__ deg,
                             const float* __restrict__ W1, short* __restrict__ P1,
                             const float* __restrict__ W2, short* __restrict__ P2,
                             const float* __restrict__ Wf1, short* __restrict__ P3,
                             const float* __restrict__ Wf2, short* __restrict__ P4) {
    int bid = blockIdx.x;
    if (bid < NB_DEG) {
        int e = bid * 256 + threadIdx.x;
        if (e < NE) atomicAdd(&deg[dst[e]], 1);
        return;
    }
    bid -= NB_DEG;
    int idx = bid * 256 + threadIdx.x;
    if (idx < S1) { pack_one(W1, P1, F0, F0, 3, 8, idx); return; }
    idx -= S1;
    if (idx < S2) { pack_one(W2, P2, F0, F2, 3, 56, idx); return; }
    idx -= S2;
    if (idx < S3) { pack_one(Wf1, P3, 1680, FH, 53, 64, idx); return; }
    idx -= S3;
    if (idx < S4) { pack_one(Wf2, P4, FH, FO, 32, 24, idx); return; }
}

// ---- scan phase 1 ----
__global__ void scan_ph1(const int* __restrict__ deg, int* __restrict__ rowptr,
                         int* __restrict__ bsum) {
    __shared__ int s[1024];
    int t = threadIdx.x;
    int i = blockIdx.x * 1024 + t;
    int v = (i < NN) ? deg[i] : 0;
    s[t] = v;
    __syncthreads();
    for (int d = 1; d < 1024; d <<= 1) {
        int u = (t >= d) ? s[t - d] : 0;
        __syncthreads();
        s[t] += u;
        __syncthreads();
    }
    if (i < NN) rowptr[i] = s[t] - v;
    if (t == 1023) bsum[blockIdx.x] = s[t];
}

// ---- scan phase 2+3 (also zeroes cnt for edge_fill) ----
__global__ void scan_ph23(int* __restrict__ rowptr, const int* __restrict__ bsum,
                          int* __restrict__ cnt, int nb) {
    __shared__ int s[128];
    int t = threadIdx.x;
    int b = blockIdx.x;
    if (t < 128) s[t] = (t < b && t < nb) ? bsum[t] : 0;
    __syncthreads();
    for (int d = 64; d >= 1; d >>= 1) {
        if (t < d) s[t] += s[t + d];
        __syncthreads();
    }
    int off = s[0];
    int i = b * 1024 + t;
    if (i < NN) {
        rowptr[i] += off;
        cnt[i] = 0;
    }
    if (i == 0) rowptr[NN] = NE;
}

__global__ void edge_fill(const int* __restrict__ src, const int* __restrict__ dst,
                          const int* __restrict__ rowptr, int* __restrict__ cnt,
                          int* __restrict__ eid) {
    int e = blockIdx.x * blockDim.x + threadIdx.x;
    if (e >= NE) return;
    int d = dst[e];
    int p = rowptr[d] + atomicAdd(&cnt[d], 1);
    eid[p] = src[e];
}

// ---- gather item from fp32 x (conv1): W pad rows are zero, so upper-half
// garbage in chunk 10 and all of chunk 11 contribute nothing ----
__device__ inline void gather_item_f32(const float* __restrict__ X,
                                       const int* __restrict__ rowptr,
                                       const int* __restrict__ eid,
                                       int n, int r, int c, short* __restrict__ ldsTile) {
    int kb = c >> 2, q = c & 3;
    short* slot = &ldsTile[kb * 512 + (q * 16 + r) * 8];
    if (c == 11) {
        bf16x8 z = {0, 0, 0, 0, 0, 0, 0, 0};
        *reinterpret_cast<bf16x8*>(slot) = z;
        return;
    }
    int k0 = c * 8;
    const float* base = X + (size_t)n * F0 + k0;
    float4 sa = *reinterpret_cast<const float4*>(base);
    float4 sb = *reinterpret_cast<const float4*>(base + 4);
    float acc[8] = {sa.x, sa.y, sa.z, sa.w, sb.x, sb.y, sb.z, sb.w};
    int e0 = rowptr[n], e1 = rowptr[n + 1];
    int e = e0;
    for (; e + 1 < e1; e += 2) {
        int s0 = eid[e], s1 = eid[e + 1];
        const float* p0 = X + (size_t)s0 * F0 + k0;
        const float* p1 = X + (size_t)s1 * F0 + k0;
        float4 a0 = *reinterpret_cast<const float4*>(p0);
        float4 b0 = *reinterpret_cast<const float4*>(p0 + 4);
        float4 a1 = *reinterpret_cast<const float4*>(p1);
        float4 b1 = *reinterpret_cast<const float4*>(p1 + 4);
        acc[0] += a0.x + a1.x; acc[1] += a0.y + a1.y;
        acc[2] += a0.z + a1.z; acc[3] += a0.w + a1.w;
        acc[4] += b0.x + b1.x; acc[5] += b0.y + b1.y;
        acc[6] += b0.z + b1.z; acc[7] += b0.w + b1.w;
    }
    if (e < e1) {
        int s0 = eid[e];
        const float* p0 = X + (size_t)s0 * F0 + k0;
        float4 a0 = *reinterpret_cast<const float4*>(p0);
        float4 b0 = *reinterpret_cast<const float4*>(p0 + 4);
        acc[0] += a0.x; acc[1] += a0.y; acc[2] += a0.z; acc[3] += a0.w;
        acc[4] += b0.x; acc[5] += b0.y; acc[6] += b0.z; acc[7] += b0.w;
    }
    bf16x8 o;
#pragma unroll
    for (int j = 0; j < 8; ++j) o[j] = f2bf(acc[j]);
    *reinterpret_cast<bf16x8*>(slot) = o;
}

// ---- gather item from bf16 H (conv2) ----
__device__ inline void gather_item(const short* __restrict__ H,
                                   const int* __restrict__ rowptr,
                                   const int* __restrict__ eid,
                                   int n, int r, int c, short* __restrict__ ldsTile) {
    int off = c * 8;
    bf16x8 sv = *reinterpret_cast<const bf16x8*>(H + (size_t)n * 96 + off);
    float acc[8];
#pragma unroll
    for (int j = 0; j < 8; ++j) acc[j] = b2f(sv[j]);
    int e0 = rowptr[n], e1 = rowptr[n + 1];
    int e = e0;
    for (; e + 1 < e1; e += 2) {
        int s0 = eid[e], s1 = eid[e + 1];
        bf16x8 v0 = *reinterpret_cast<const bf16x8*>(H + (size_t)s0 * 96 + off);
        bf16x8 v1 = *reinterpret_cast<const bf16x8*>(H + (size_t)s1 * 96 + off);
#pragma unroll
        for (int j = 0; j < 8; ++j) acc[j] += b2f(v0[j]) + b2f(v1[j]);
    }
    if (e < e1) {
        int s0 = eid[e];
        bf16x8 v0 = *reinterpret_cast<const bf16x8*>(H + (size_t)s0 * 96 + off);
#pragma unroll
        for (int j = 0; j < 8; ++j) acc[j] += b2f(v0[j]);
    }
    bf16x8 o;
#pragma unroll
    for (int j = 0; j < 8; ++j) o[j] = f2bf(acc[j]);
    int kb = c >> 2, q = c & 3;
    *reinterpret_cast<bf16x8*>(&ldsTile[kb * 512 + (q * 16 + r) * 8]) = o;
}

// ---- conv1: fused fp32-gather + gemm, 4 waves, one 16-row tile, CTW=2 ----
__global__ __launch_bounds__(256) void conv1_f32(
        const float* __restrict__ X, const int* __restrict__ rowptr,
        const int* __restrict__ eid, const short* __restrict__ Bp,
        const float* __restrict__ bias, short* __restrict__ Cout) {
    __shared__ short Alds[3 * 512];
    int rt = blockIdx.x;
    int t  = threadIdx.x;

    if (t < 192) {
        int r = t / 12;
        int c = t - r * 12;
        gather_item_f32(X, rowptr, eid, rt * 16 + r, r, c, Alds);
    }
    __syncthreads();

    int wave = t >> 6;
    int lane = t & 63;
    f32x4 acc[2];
#pragma unroll
    for (int u = 0; u < 2; ++u) acc[u] = (f32x4){0.f, 0.f, 0.f, 0.f};
    const short* Bbase = Bp + (size_t)(wave * 2) * 3 * 512 + lane * 8;
#pragma unroll
    for (int kb = 0; kb < 3; ++kb) {
        bf16x8 a = *reinterpret_cast<const bf16x8*>(&Alds[kb * 512 + lane * 8]);
#pragma unroll
        for (int u = 0; u < 2; ++u) {
            bf16x8 b = *reinterpret_cast<const bf16x8*>(Bbase + ((size_t)u * 3 + kb) * 512);
            acc[u] = __builtin_amdgcn_mfma_f32_16x16x32_bf16(a, b, acc[u], 0, 0, 0);
        }
    }
    int row0 = rt * 16 + ((lane >> 4) << 2);
#pragma unroll
    for (int u = 0; u < 2; ++u) {
        int col = (wave * 2 + u) * 16 + (lane & 15);
        if (col < 96) {   // guard: cols 96..127 would alias into the next row
            float bi = (col < F0) ? bias[col] : 0.f;
#pragma unroll
            for (int r = 0; r < 4; ++r) {
                float v = fmaxf(acc[u][r] + bi, 0.f);
                Cout[(size_t)(row0 + r) * 96 + col] = f2bf(v);
            }
        }
    }
}

// ---- conv2: 8 waves x CTW=7, TWO 16-row tiles per block (B reused 2x) ----
__global__ __launch_bounds__(512, 4) void conv2_part(
        const short* __restrict__ H, const int* __restrict__ rowptr,
        const int* __restrict__ eid, const short* __restrict__ Bp,
        const float* __restrict__ bias, float* __restrict__ h2,
        float* __restrict__ Pmax, float* __restrict__ Psum) {
    __shared__ short Alds[2][3 * 512];
    int bb = blockIdx.x;      // covers rows bb*32 .. bb*32+31
    int t  = threadIdx.x;
    int base = bb * 32;

    if (t < 384) {
        int tile = t >= 192;
        int it   = t - (tile ? 192 : 0);
        int r = it / 12;
        int c = it - r * 12;
        gather_item(H, rowptr, eid, base + tile * 16 + r, r, c, Alds[tile]);
    }
    __syncthreads();

    int wave = t >> 6;   // 0..7
    int lane = t & 63;
    f32x4 acc0[7], acc1[7];
#pragma unroll
    for (int u = 0; u < 7; ++u) {
        acc0[u] = (f32x4){0.f, 0.f, 0.f, 0.f};
        acc1[u] = (f32x4){0.f, 0.f, 0.f, 0.f};
    }
    const short* Bbase = Bp + (size_t)(wave * 7) * 3 * 512 + lane * 8;
#pragma unroll
    for (int kb = 0; kb < 3; ++kb) {
        bf16x8 a0 = *reinterpret_cast<const bf16x8*>(&Alds[0][kb * 512 + lane * 8]);
        bf16x8 a1 = *reinterpret_cast<const bf16x8*>(&Alds[1][kb * 512 + lane * 8]);
#pragma unroll
        for (int u = 0; u < 7; ++u) {
            bf16x8 b = *reinterpret_cast<const bf16x8*>(Bbase + ((size_t)u * 3 + kb) * 512);
            acc0[u] = __builtin_amdgcn_mfma_f32_16x16x32_bf16(a0, b, acc0[u], 0, 0, 0);
            acc1[u] = __builtin_amdgcn_mfma_f32_16x16x32_bf16(a1, b, acc1[u], 0, 0, 0);
        }
    }
    int rg = (lane >> 4) << 2;
    int colb = wave * 7 * 16 + (lane & 15);
    // ---- tile 0 epilogue ----
#pragma unroll
    for (int u = 0; u < 7; ++u) {
        int col = colb + u * 16;
        if (col < F2) {
            float bi = bias[col];
            float m = -INFINITY, sm = 0.f;
            int row0 = base + rg;
#pragma unroll
            for (int r = 0; r < 4; ++r) {
                float v = fmaxf(acc0[u][r] + bi, 0.f);
                h2[(size_t)(row0 + r) * F2 + col] = v;
                m = fmaxf(m, v);
                sm += v;
            }
            m = fmaxf(m, __shfl_xor(m, 16));
            m = fmaxf(m, __shfl_xor(m, 32));
            sm += __shfl_xor(sm, 16);
            sm += __shfl_xor(sm, 32);
            if (lane < 16) {
                Pmax[(size_t)(bb * 2) * F2 + col] = m;
                Psum[(size_t)(bb * 2) * F2 + col] = sm;
            }
        }
    }
    // ---- tile 1 epilogue ----
#pragma unroll
    for (int u = 0; u < 7; ++u) {
        int col = colb + u * 16;
        if (col < F2) {
            float bi = bias[col];
            float m = -INFINITY, sm = 0.f;
            int row0 = base + 16 + rg;
#pragma unroll
            for (int r = 0; r < 4; ++r) {
                float v = fmaxf(acc1[u][r] + bi, 0.f);
                h2[(size_t)(row0 + r) * F2 + col] = v;
                m = fmaxf(m, v);
                sm += v;
            }
            m = fmaxf(m, __shfl_xor(m, 16));
            m = fmaxf(m, __shfl_xor(m, 32));
            sm += __shfl_xor(sm, 16);
            sm += __shfl_xor(sm, 32);
            if (lane < 16) {
                Pmax[(size_t)(bb * 2 + 1) * F2 + col] = m;
                Psum[(size_t)(bb * 2 + 1) * F2 + col] = sm;
            }
        }
    }
}

// ---- pool: per graph; full tiles from partials, boundary rows from h2 ----
__global__ void pool_kernel(const float* __restrict__ h2,
                            const int* __restrict__ batch,
                            const float* __restrict__ Pmax,
                            const float* __restrict__ Psum,
                            short* __restrict__ A3) {
    int g = blockIdx.x;
    int t = threadIdx.x;  // 256
    __shared__ int se[2];
    if (t < 2) {
        int target = g + t;
        int lo = 0, hi = NN;
        while (lo < hi) {
            int mid = (lo + hi) >> 1;
            if (batch[mid] < target) lo = mid + 1; else hi = mid;
        }
        se[t] = lo;
    }
    __syncthreads();
    int s = se[0], e = se[1];
    int t0 = (s + 15) >> 4;   // first full tile
    int t1 = e >> 4;          // end of full tiles
    if (t < 210) {
        int c4 = t * 4;
        float sm0 = 0.f, sm1 = 0.f, sm2 = 0.f, sm3 = 0.f;
        float mx0 = -INFINITY, mx1 = -INFINITY, mx2 = -INFINITY, mx3 = -INFINITY;
        if (t1 >= t0) {
            for (int tile = t0; tile < t1; ++tile) {
                float4 pm = *reinterpret_cast<const float4*>(Pmax + (size_t)tile * F2 + c4);
                float4 ps = *reinterpret_cast<const float4*>(Psum + (size_t)tile * F2 + c4);
                mx0 = fmaxf(mx0, pm.x); mx1 = fmaxf(mx1, pm.y);
                mx2 = fmaxf(mx2, pm.z); mx3 = fmaxf(mx3, pm.w);
                sm0 += ps.x; sm1 += ps.y; sm2 += ps.z; sm3 += ps.w;
            }
            for (int n = s; n < (t0 << 4); ++n) {
                float4 v = *reinterpret_cast<const float4*>(h2 + (size_t)n * F2 + c4);
                sm0 += v.x; sm1 += v.y; sm2 += v.z; sm3 += v.w;
                mx0 = fmaxf(mx0, v.x); mx1 = fmaxf(mx1, v.y);
                mx2 = fmaxf(mx2, v.z); mx3 = fmaxf(mx3, v.w);
            }
            for (int n = (t1 << 4); n < e; ++n) {
                float4 v = *reinterpret_cast<const float4*>(h2 + (size_t)n * F2 + c4);
                sm0 += v.x; sm1 += v.y; sm2 += v.z; sm3 += v.w;
                mx0 = fmaxf(mx0, v.x); mx1 = fmaxf(mx1, v.y);
                mx2 = fmaxf(mx2, v.z); mx3 = fmaxf(mx3, v.w);
            }
        } else {
            for (int n = s; n < e; ++n) {
                float4 v = *reinterpret_cast<const float4*>(h2 + (size_t)n * F2 + c4);
                sm0 += v.x; sm1 += v.y; sm2 += v.z; sm3 += v.w;
                mx0 = fmaxf(mx0, v.x); mx1 = fmaxf(mx1, v.y);
                mx2 = fmaxf(mx2, v.z); mx3 = fmaxf(mx3, v.w);
            }
        }
        short* xr = A3 + (size_t)g * 1696;
        short4 mo, so;
        mo.x = f2bf(mx0); mo.y = f2bf(mx1); mo.z = f2bf(mx2); mo.w = f2bf(mx3);
        so.x = f2bf(sm0); so.y = f2bf(sm1); so.z = f2bf(sm2); so.w = f2bf(sm3);
        *reinterpret_cast<short4*>(xr + c4)      = mo;
        *reinterpret_cast<short4*>(xr + F2 + c4) = so;
    }
    if (t >= 210 && t < 214) {
        short4 z = {0, 0, 0, 0};
        *reinterpret_cast<short4*>(A3 + (size_t)g * 1696 + 1680 + (t - 210) * 4) = z;
    }
}

// ---- plain MFMA GEMM (fc head) ----
template <int CTW, bool RELU, bool OUTBF16>
__global__ void gemmN(const short* __restrict__ A, const short* __restrict__ Bp,
                      const float* __restrict__ bias, void* __restrict__ Cout,
                      int Kp, int Nbias, int ldc, int ncols,
                      int rowTiles, int ctGroups) {
    int gid = blockIdx.x * blockDim.x + threadIdx.x;
    int w   = gid >> 6;
    if (w >= rowTiles * ctGroups) return;
    int lane = gid & 63;
    int rt = w / ctGroups;
    int cg = w - rt * ctGroups;
    int KB = Kp >> 5;
    const short* Ap = A + (size_t)(rt * 16 + (lane & 15)) * Kp + ((lane >> 4) << 3);
    const short* Bbase = Bp + (size_t)(cg * CTW) * KB * 512 + lane * 8;
    f32x4 acc[CTW];
#pragma unroll
    for (int u = 0; u < CTW; ++u) acc[u] = (f32x4){0.f, 0.f, 0.f, 0.f};
    for (int kb = 0; kb < KB; ++kb) {
        bf16x8 a = *reinterpret_cast<const bf16x8*>(Ap + kb * 32);
#pragma unroll
        for (int u = 0; u < CTW; ++u) {
            bf16x8 b = *reinterpret_cast<const bf16x8*>(Bbase + ((size_t)u * KB + kb) * 512);
            acc[u] = __builtin_amdgcn_mfma_f32_16x16x32_bf16(a, b, acc[u], 0, 0, 0);
        }
    }
    int row0 = rt * 16 + ((lane >> 4) << 2);
#pragma unroll
    for (int u = 0; u < CTW; ++u) {
        int col = (cg * CTW + u) * 16 + (lane & 15);
        float bi = (col < Nbias) ? bias[col] : 0.f;
        if (col < ncols) {
#pragma unroll
            for (int r = 0; r < 4; ++r) {
                int row = row0 + r;
                float v = acc[u][r] + bi;
                if (RELU) v = fmaxf(v, 0.f);
                if (OUTBF16) ((short*)Cout)[(size_t)row * ldc + col] = f2bf(v);
                else         ((float*)Cout)[(size_t)row * ldc + col] = v;
            }
        }
    }
}

extern "C" void kernel_launch(void* const* d_in, const int* in_sizes, int n_in,
                              void* d_out, int out_size, void* d_ws, size_t ws_size,
                              hipStream_t stream) {
    const float* x    = (const float*)d_in[0];
    const int*   ei   = (const int*)d_in[1];
    const int*   batch= (const int*)d_in[2];
    const float* W1   = (const float*)d_in[3];
    const float* b1   = (const float*)d_in[4];
    const float* W2   = (const float*)d_in[5];
    const float* b2   = (const float*)d_in[6];
    const float* Wf1  = (const float*)d_in[7];
    const float* bf1  = (const float*)d_in[8];
    const float* Wf2  = (const float*)d_in[9];
    const float* bf2  = (const float*)d_in[10];

    const int* src = ei;
    const int* dst = ei + NE;

    float* xg_out = (float*)d_out;                    // [NG, FO]
    float* h2     = (float*)d_out + (size_t)NG * FO;  // [NN, F2] fp32

    // workspace layout (Xb removed)
    short* h1   = (short*)d_ws;                        // NN*96
    short* A3   = h1 + (size_t)NN * 96;                // NG*1696
    short* fc1o = A3 + (size_t)NG * 1696;              // NG*1024
    short* W1p  = fc1o + (size_t)NG * FH;              // S1*8
    short* W2p  = W1p + (size_t)S1 * 8;                // S2*8
    short* Wf1p = W2p + (size_t)S2 * 8;                // S3*8
    short* Wf2p = Wf1p + (size_t)S3 * 8;               // S4*8
    int*   deg  = (int*)(Wf2p + (size_t)S4 * 8);       // NN
    int*   cnt  = deg + NN;                            // NN
    int*   rowptr = cnt + NN;                          // NN+1
    int*   bsum = rowptr + NN + 1;                     // 128
    int*   eid  = bsum + 128;                          // NE
    float* Pmax = (float*)(eid + NE);                  // NT2*840
    float* Psum = Pmax + (size_t)NT2 * F2;             // NT2*840

    const int blk = 256;
    auto cdiv = [](long long a, long long b) { return (int)((a + b - 1) / b); };
    const int nb1024 = cdiv(NN, 1024);  // 98

    // ---- front: zero deg, then deg || pack ----
    hipMemsetAsync(deg, 0, (size_t)NN * sizeof(int), stream);
    front_kernel<<<NB_DEG + NB_PACK, blk, 0, stream>>>(
        dst, deg, W1, W1p, W2, W2p, Wf1, Wf1p, Wf2, Wf2p);

    // ---- CSR scan + fill ----
    scan_ph1<<<nb1024, 1024, 0, stream>>>(deg, rowptr, bsum);
    scan_ph23<<<nb1024, 1024, 0, stream>>>(rowptr, bsum, cnt, nb1024);
    edge_fill<<<cdiv(NE, blk), blk, 0, stream>>>(src, dst, rowptr, cnt, eid);

    // ---- conv1 (fp32 gather direct from x): h1 = bf16(relu((x+gather)@W1+b1)) ----
    conv1_f32<<<NT2, 256, 0, stream>>>(x, rowptr, eid, W1p, b1, h1);

    // ---- conv2 (8 waves x CTW=7, 2 row-tiles/block) + per-tile partial pool ----
    conv2_part<<<NT2 / 2, 512, 0, stream>>>(h1, rowptr, eid, W2p, b2, h2, Pmax, Psum);

    // ---- pooling from partials + boundary rows ----
    pool_kernel<<<NG, blk, 0, stream>>>(h2, batch, Pmax, Psum, A3);

    // ---- fc head ----
    gemmN<2, true, true><<<cdiv(125LL * 32 * 64, blk), blk, 0, stream>>>(
        A3, Wf1p, bf1, fc1o, 1696, FH, FH, FH, 125, 32);
    gemmN<2, false, false><<<cdiv(125LL * 12 * 64, blk), blk, 0, stream>>>(
        fc1o, Wf2p, bf2, xg_out, 1024, FO, FO, FO, 125, 12);
}

// Round 16
// 334.154 us; speedup vs baseline: 1.1030x; 1.0096x over previous
//
#include <hip/hip_runtime.h>
#include <math.h>

#define NN 100000   // nodes
#define NE 400000   // edges
#define NG 2000     // graphs
#define F0 84       // num_features_xd
#define F2 840      // F0*10
#define FH 1024     // fc hidden
#define FO 384      // fc out
#define NT2 6250    // row tiles (NN/16)

typedef __attribute__((ext_vector_type(8))) short bf16x8;
typedef __attribute__((ext_vector_type(4))) float f32x4;

__device__ inline short f2bf(float f) {
    union { float f; unsigned u; } v; v.f = f;
    unsigned r = (v.u + 0x7FFFu + ((v.u >> 16) & 1u)) >> 16;
    return (short)r;
}
__device__ inline float b2f(short s) {
    union { unsigned u; float f; } v;
    v.u = ((unsigned)(unsigned short)s) << 16;
    return v.f;
}

// ---- pack geometry ----
#define S1 (8*3*64)
#define S2 (56*3*64)
#define S3 (64*53*64)
#define S4 (24*32*64)
#define PACK_TOT (S1 + S2 + S3 + S4)     // 278528
#define NB_DEG  1563                     // ceil(NE/256)
#define NB_PACK 1088                     // ceil(PACK_TOT/256)

__device__ inline void pack_one(const float* __restrict__ W, short* __restrict__ P,
                                int K, int N, int KB, int CT, int idx) {
    int lane = idx & 63;
    int t    = idx >> 6;
    int kb   = t % KB;
    int ct   = t / KB;
    int col  = ct * 16 + (lane & 15);
    int k0   = kb * 32 + ((lane >> 4) << 3);
    bf16x8 v;
#pragma unroll
    for (int j = 0; j < 8; ++j) {
        int k = k0 + j;
        float f = (k < K && col < N) ? W[(size_t)k * N + col] : 0.f;
        v[j] = f2bf(f);
    }
    *reinterpret_cast<bf16x8*>(P + (size_t)idx * 8) = v;
}

// ---- front: edge_deg || pack_all ----
__global__ void front_kernel(const int* __restrict__ dst, int* __restrict__ deg,
                             const float* __restrict__ W1, short* __restrict__ P1,
                             const float* __restrict__ W2, short* __restrict__ P2,
                             const float* __restrict__ Wf1, short* __restrict__ P3,
                             const float* __restrict__ Wf2, short* __restrict__ P4) {
    int bid = blockIdx.x;
    if (bid < NB_DEG) {
        int e = bid * 256 + threadIdx.x;
        if (e < NE) atomicAdd(&deg[dst[e]], 1);
        return;
    }
    bid -= NB_DEG;
    int idx = bid * 256 + threadIdx.x;
    if (idx < S1) { pack_one(W1, P1, F0, F0, 3, 8, idx); return; }
    idx -= S1;
    if (idx < S2) { pack_one(W2, P2, F0, F2, 3, 56, idx); return; }
    idx -= S2;
    if (idx < S3) { pack_one(Wf1, P3, 1680, FH, 53, 64, idx); return; }
    idx -= S3;
    if (idx < S4) { pack_one(Wf2, P4, FH, FO, 32, 24, idx); return; }
}

// ---- scan phase 1 ----
__global__ void scan_ph1(const int* __restrict__ deg, int* __restrict__ rowptr,
                         int* __restrict__ bsum) {
    __shared__ int s[1024];
    int t = threadIdx.x;
    int i = blockIdx.x * 1024 + t;
    int v = (i < NN) ? deg[i] : 0;
    s[t] = v;
    __syncthreads();
    for (int d = 1; d < 1024; d <<= 1) {
        int u = (t >= d) ? s[t - d] : 0;
        __syncthreads();
        s[t] += u;
        __syncthreads();
    }
    if (i < NN) rowptr[i] = s[t] - v;
    if (t == 1023) bsum[blockIdx.x] = s[t];
}

// ---- scan phase 2+3 (also zeroes cnt for edge_fill) ----
__global__ void scan_ph23(int* __restrict__ rowptr, const int* __restrict__ bsum,
                          int* __restrict__ cnt, int nb) {
    __shared__ int s[128];
    int t = threadIdx.x;
    int b = blockIdx.x;
    if (t < 128) s[t] = (t < b && t < nb) ? bsum[t] : 0;
    __syncthreads();
    for (int d = 64; d >= 1; d >>= 1) {
        if (t < d) s[t] += s[t + d];
        __syncthreads();
    }
    int off = s[0];
    int i = b * 1024 + t;
    if (i < NN) {
        rowptr[i] += off;
        cnt[i] = 0;
    }
    if (i == 0) rowptr[NN] = NE;
}

__global__ void edge_fill(const int* __restrict__ src, const int* __restrict__ dst,
                          const int* __restrict__ rowptr, int* __restrict__ cnt,
                          int* __restrict__ eid) {
    int e = blockIdx.x * blockDim.x + threadIdx.x;
    if (e >= NE) return;
    int d = dst[e];
    int p = rowptr[d] + atomicAdd(&cnt[d], 1);
    eid[p] = src[e];
}

// ---- gather cores (edge-source provided by functor: LDS-staged or global) ----
template <typename EF>
__device__ inline void gather_core_f32(const float* __restrict__ X, int k0,
                                       int e0, int e1, float* acc, EF srcOf) {
    int e = e0;
    for (; e + 1 < e1; e += 2) {
        int s0 = srcOf(e), s1 = srcOf(e + 1);
        const float* p0 = X + (size_t)s0 * F0 + k0;
        const float* p1 = X + (size_t)s1 * F0 + k0;
        float4 a0 = *reinterpret_cast<const float4*>(p0);
        float4 b0 = *reinterpret_cast<const float4*>(p0 + 4);
        float4 a1 = *reinterpret_cast<const float4*>(p1);
        float4 b1 = *reinterpret_cast<const float4*>(p1 + 4);
        acc[0] += a0.x + a1.x; acc[1] += a0.y + a1.y;
        acc[2] += a0.z + a1.z; acc[3] += a0.w + a1.w;
        acc[4] += b0.x + b1.x; acc[5] += b0.y + b1.y;
        acc[6] += b0.z + b1.z; acc[7] += b0.w + b1.w;
    }
    if (e < e1) {
        int s0 = srcOf(e);
        const float* p0 = X + (size_t)s0 * F0 + k0;
        float4 a0 = *reinterpret_cast<const float4*>(p0);
        float4 b0 = *reinterpret_cast<const float4*>(p0 + 4);
        acc[0] += a0.x; acc[1] += a0.y; acc[2] += a0.z; acc[3] += a0.w;
        acc[4] += b0.x; acc[5] += b0.y; acc[6] += b0.z; acc[7] += b0.w;
    }
}

template <typename EF>
__device__ inline void gather_core_bf16(const short* __restrict__ H, int off,
                                        int e0, int e1, float* acc, EF srcOf) {
    int e = e0;
    for (; e + 1 < e1; e += 2) {
        int s0 = srcOf(e), s1 = srcOf(e + 1);
        bf16x8 v0 = *reinterpret_cast<const bf16x8*>(H + (size_t)s0 * 96 + off);
        bf16x8 v1 = *reinterpret_cast<const bf16x8*>(H + (size_t)s1 * 96 + off);
#pragma unroll
        for (int j = 0; j < 8; ++j) acc[j] += b2f(v0[j]) + b2f(v1[j]);
    }
    if (e < e1) {
        int s0 = srcOf(e);
        bf16x8 v0 = *reinterpret_cast<const bf16x8*>(H + (size_t)s0 * 96 + off);
#pragma unroll
        for (int j = 0; j < 8; ++j) acc[j] += b2f(v0[j]);
    }
}

// ---- conv1: fused fp32-gather + gemm, 4 waves, one 16-row tile, CTW=2 ----
// Edge IDs for the tile's 16 rows staged into LDS (contiguous CSR range).
#define ECAP1 1024
__global__ __launch_bounds__(256) void conv1_f32(
        const float* __restrict__ X, const int* __restrict__ rowptr,
        const int* __restrict__ eid, const short* __restrict__ Bp,
        const float* __restrict__ bias, short* __restrict__ Cout) {
    __shared__ short Alds[3 * 512];
    __shared__ int elds[ECAP1];
    int rt = blockIdx.x;
    int t  = threadIdx.x;

    int r0   = rowptr[rt * 16];
    int etot = rowptr[rt * 16 + 16] - r0;
    bool fit = (etot <= ECAP1);
    if (fit) {
        for (int i = t; i < etot; i += 256) elds[i] = eid[r0 + i];
    }
    __syncthreads();

    if (t < 192) {
        int r = t / 12;
        int c = t - r * 12;
        int n = rt * 16 + r;
        int kb = c >> 2, q = c & 3;
        short* slot = &Alds[kb * 512 + (q * 16 + r) * 8];
        if (c == 11) {
            bf16x8 z = {0, 0, 0, 0, 0, 0, 0, 0};
            *reinterpret_cast<bf16x8*>(slot) = z;
        } else {
            int k0 = c * 8;
            const float* base = X + (size_t)n * F0 + k0;
            float4 sa = *reinterpret_cast<const float4*>(base);
            float4 sb = *reinterpret_cast<const float4*>(base + 4);
            float acc[8] = {sa.x, sa.y, sa.z, sa.w, sb.x, sb.y, sb.z, sb.w};
            int e0 = rowptr[n], e1 = rowptr[n + 1];
            if (fit) {
                gather_core_f32(X, k0, e0, e1, acc,
                                [&](int e) { return elds[e - r0]; });
            } else {
                gather_core_f32(X, k0, e0, e1, acc,
                                [&](int e) { return eid[e]; });
            }
            bf16x8 o;
#pragma unroll
            for (int j = 0; j < 8; ++j) o[j] = f2bf(acc[j]);
            *reinterpret_cast<bf16x8*>(slot) = o;
        }
    }
    __syncthreads();

    int wave = t >> 6;
    int lane = t & 63;
    f32x4 acc[2];
#pragma unroll
    for (int u = 0; u < 2; ++u) acc[u] = (f32x4){0.f, 0.f, 0.f, 0.f};
    const short* Bbase = Bp + (size_t)(wave * 2) * 3 * 512 + lane * 8;
#pragma unroll
    for (int kb = 0; kb < 3; ++kb) {
        bf16x8 a = *reinterpret_cast<const bf16x8*>(&Alds[kb * 512 + lane * 8]);
#pragma unroll
        for (int u = 0; u < 2; ++u) {
            bf16x8 b = *reinterpret_cast<const bf16x8*>(Bbase + ((size_t)u * 3 + kb) * 512);
            acc[u] = __builtin_amdgcn_mfma_f32_16x16x32_bf16(a, b, acc[u], 0, 0, 0);
        }
    }
    int row0 = rt * 16 + ((lane >> 4) << 2);
#pragma unroll
    for (int u = 0; u < 2; ++u) {
        int col = (wave * 2 + u) * 16 + (lane & 15);
        if (col < 96) {   // guard: cols 96..127 would alias into the next row
            float bi = (col < F0) ? bias[col] : 0.f;
#pragma unroll
            for (int r = 0; r < 4; ++r) {
                float v = fmaxf(acc[u][r] + bi, 0.f);
                Cout[(size_t)(row0 + r) * 96 + col] = f2bf(v);
            }
        }
    }
}

// ---- conv2: 8 waves x CTW=7, TWO 16-row tiles per block (B reused 2x);
// edge IDs for the 32 rows staged into LDS ----
#define ECAP2 2048
__global__ __launch_bounds__(512, 4) void conv2_part(
        const short* __restrict__ H, const int* __restrict__ rowptr,
        const int* __restrict__ eid, const short* __restrict__ Bp,
        const float* __restrict__ bias, float* __restrict__ h2,
        float* __restrict__ Pmax, float* __restrict__ Psum) {
    __shared__ short Alds[2][3 * 512];
    __shared__ int elds[ECAP2];
    int bb = blockIdx.x;      // covers rows bb*32 .. bb*32+31
    int t  = threadIdx.x;
    int base = bb * 32;

    int r0   = rowptr[base];
    int etot = rowptr[base + 32] - r0;
    bool fit = (etot <= ECAP2);
    if (fit) {
        for (int i = t; i < etot; i += 512) elds[i] = eid[r0 + i];
    }
    __syncthreads();

    if (t < 384) {
        int tile = t >= 192;
        int it   = t - (tile ? 192 : 0);
        int r = it / 12;
        int c = it - r * 12;
        int n = base + tile * 16 + r;
        int off = c * 8;
        bf16x8 sv = *reinterpret_cast<const bf16x8*>(H + (size_t)n * 96 + off);
        float acc[8];
#pragma unroll
        for (int j = 0; j < 8; ++j) acc[j] = b2f(sv[j]);
        int e0 = rowptr[n], e1 = rowptr[n + 1];
        if (fit) {
            gather_core_bf16(H, off, e0, e1, acc,
                             [&](int e) { return elds[e - r0]; });
        } else {
            gather_core_bf16(H, off, e0, e1, acc,
                             [&](int e) { return eid[e]; });
        }
        bf16x8 o;
#pragma unroll
        for (int j = 0; j < 8; ++j) o[j] = f2bf(acc[j]);
        int kb = c >> 2, q = c & 3;
        *reinterpret_cast<bf16x8*>(&Alds[tile][kb * 512 + (q * 16 + r) * 8]) = o;
    }
    __syncthreads();

    int wave = t >> 6;   // 0..7
    int lane = t & 63;
    f32x4 acc0[7], acc1[7];
#pragma unroll
    for (int u = 0; u < 7; ++u) {
        acc0[u] = (f32x4){0.f, 0.f, 0.f, 0.f};
        acc1[u] = (f32x4){0.f, 0.f, 0.f, 0.f};
    }
    const short* Bbase = Bp + (size_t)(wave * 7) * 3 * 512 + lane * 8;
#pragma unroll
    for (int kb = 0; kb < 3; ++kb) {
        bf16x8 a0 = *reinterpret_cast<const bf16x8*>(&Alds[0][kb * 512 + lane * 8]);
        bf16x8 a1 = *reinterpret_cast<const bf16x8*>(&Alds[1][kb * 512 + lane * 8]);
#pragma unroll
        for (int u = 0; u < 7; ++u) {
            bf16x8 b = *reinterpret_cast<const bf16x8*>(Bbase + ((size_t)u * 3 + kb) * 512);
            acc0[u] = __builtin_amdgcn_mfma_f32_16x16x32_bf16(a0, b, acc0[u], 0, 0, 0);
            acc1[u] = __builtin_amdgcn_mfma_f32_16x16x32_bf16(a1, b, acc1[u], 0, 0, 0);
        }
    }
    int rg = (lane >> 4) << 2;
    int colb = wave * 7 * 16 + (lane & 15);
    // ---- tile 0 epilogue ----
#pragma unroll
    for (int u = 0; u < 7; ++u) {
        int col = colb + u * 16;
        if (col < F2) {
            float bi = bias[col];
            float m = -INFINITY, sm = 0.f;
            int row0 = base + rg;
#pragma unroll
            for (int r = 0; r < 4; ++r) {
                float v = fmaxf(acc0[u][r] + bi, 0.f);
                h2[(size_t)(row0 + r) * F2 + col] = v;
                m = fmaxf(m, v);
                sm += v;
            }
            m = fmaxf(m, __shfl_xor(m, 16));
            m = fmaxf(m, __shfl_xor(m, 32));
            sm += __shfl_xor(sm, 16);
            sm += __shfl_xor(sm, 32);
            if (lane < 16) {
                Pmax[(size_t)(bb * 2) * F2 + col] = m;
                Psum[(size_t)(bb * 2) * F2 + col] = sm;
            }
        }
    }
    // ---- tile 1 epilogue ----
#pragma unroll
    for (int u = 0; u < 7; ++u) {
        int col = colb + u * 16;
        if (col < F2) {
            float bi = bias[col];
            float m = -INFINITY, sm = 0.f;
            int row0 = base + 16 + rg;
#pragma unroll
            for (int r = 0; r < 4; ++r) {
                float v = fmaxf(acc1[u][r] + bi, 0.f);
                h2[(size_t)(row0 + r) * F2 + col] = v;
                m = fmaxf(m, v);
                sm += v;
            }
            m = fmaxf(m, __shfl_xor(m, 16));
            m = fmaxf(m, __shfl_xor(m, 32));
            sm += __shfl_xor(sm, 16);
            sm += __shfl_xor(sm, 32);
            if (lane < 16) {
                Pmax[(size_t)(bb * 2 + 1) * F2 + col] = m;
                Psum[(size_t)(bb * 2 + 1) * F2 + col] = sm;
            }
        }
    }
}

// ---- pool: per graph; full tiles from partials, boundary rows from h2 ----
__global__ void pool_kernel(const float* __restrict__ h2,
                            const int* __restrict__ batch,
                            const float* __restrict__ Pmax,
                            const float* __restrict__ Psum,
                            short* __restrict__ A3) {
    int g = blockIdx.x;
    int t = threadIdx.x;  // 256
    __shared__ int se[2];
    if (t < 2) {
        int target = g + t;
        int lo = 0, hi = NN;
        while (lo < hi) {
            int mid = (lo + hi) >> 1;
            if (batch[mid] < target) lo = mid + 1; else hi = mid;
        }
        se[t] = lo;
    }
    __syncthreads();
    int s = se[0], e = se[1];
    int t0 = (s + 15) >> 4;   // first full tile
    int t1 = e >> 4;          // end of full tiles
    if (t < 210) {
        int c4 = t * 4;
        float sm0 = 0.f, sm1 = 0.f, sm2 = 0.f, sm3 = 0.f;
        float mx0 = -INFINITY, mx1 = -INFINITY, mx2 = -INFINITY, mx3 = -INFINITY;
        if (t1 >= t0) {
            for (int tile = t0; tile < t1; ++tile) {
                float4 pm = *reinterpret_cast<const float4*>(Pmax + (size_t)tile * F2 + c4);
                float4 ps = *reinterpret_cast<const float4*>(Psum + (size_t)tile * F2 + c4);
                mx0 = fmaxf(mx0, pm.x); mx1 = fmaxf(mx1, pm.y);
                mx2 = fmaxf(mx2, pm.z); mx3 = fmaxf(mx3, pm.w);
                sm0 += ps.x; sm1 += ps.y; sm2 += ps.z; sm3 += ps.w;
            }
            for (int n = s; n < (t0 << 4); ++n) {
                float4 v = *reinterpret_cast<const float4*>(h2 + (size_t)n * F2 + c4);
                sm0 += v.x; sm1 += v.y; sm2 += v.z; sm3 += v.w;
                mx0 = fmaxf(mx0, v.x); mx1 = fmaxf(mx1, v.y);
                mx2 = fmaxf(mx2, v.z); mx3 = fmaxf(mx3, v.w);
            }
            for (int n = (t1 << 4); n < e; ++n) {
                float4 v = *reinterpret_cast<const float4*>(h2 + (size_t)n * F2 + c4);
                sm0 += v.x; sm1 += v.y; sm2 += v.z; sm3 += v.w;
                mx0 = fmaxf(mx0, v.x); mx1 = fmaxf(mx1, v.y);
                mx2 = fmaxf(mx2, v.z); mx3 = fmaxf(mx3, v.w);
            }
        } else {
            for (int n = s; n < e; ++n) {
                float4 v = *reinterpret_cast<const float4*>(h2 + (size_t)n * F2 + c4);
                sm0 += v.x; sm1 += v.y; sm2 += v.z; sm3 += v.w;
                mx0 = fmaxf(mx0, v.x); mx1 = fmaxf(mx1, v.y);
                mx2 = fmaxf(mx2, v.z); mx3 = fmaxf(mx3, v.w);
            }
        }
        short* xr = A3 + (size_t)g * 1696;
        short4 mo, so;
        mo.x = f2bf(mx0); mo.y = f2bf(mx1); mo.z = f2bf(mx2); mo.w = f2bf(mx3);
        so.x = f2bf(sm0); so.y = f2bf(sm1); so.z = f2bf(sm2); so.w = f2bf(sm3);
        *reinterpret_cast<short4*>(xr + c4)      = mo;
        *reinterpret_cast<short4*>(xr + F2 + c4) = so;
    }
    if (t >= 210 && t < 214) {
        short4 z = {0, 0, 0, 0};
        *reinterpret_cast<short4*>(A3 + (size_t)g * 1696 + 1680 + (t - 210) * 4) = z;
    }
}

// ---- plain MFMA GEMM (fc head) ----
template <int CTW, bool RELU, bool OUTBF16>
__global__ void gemmN(const short* __restrict__ A, const short* __restrict__ Bp,
                      const float* __restrict__ bias, void* __restrict__ Cout,
                      int Kp, int Nbias, int ldc, int ncols,
                      int rowTiles, int ctGroups) {
    int gid = blockIdx.x * blockDim.x + threadIdx.x;
    int w   = gid >> 6;
    if (w >= rowTiles * ctGroups) return;
    int lane = gid & 63;
    int rt = w / ctGroups;
    int cg = w - rt * ctGroups;
    int KB = Kp >> 5;
    const short* Ap = A + (size_t)(rt * 16 + (lane & 15)) * Kp + ((lane >> 4) << 3);
    const short* Bbase = Bp + (size_t)(cg * CTW) * KB * 512 + lane * 8;
    f32x4 acc[CTW];
#pragma unroll
    for (int u = 0; u < CTW; ++u) acc[u] = (f32x4){0.f, 0.f, 0.f, 0.f};
    for (int kb = 0; kb < KB; ++kb) {
        bf16x8 a = *reinterpret_cast<const bf16x8*>(Ap + kb * 32);
#pragma unroll
        for (int u = 0; u < CTW; ++u) {
            bf16x8 b = *reinterpret_cast<const bf16x8*>(Bbase + ((size_t)u * KB + kb) * 512);
            acc[u] = __builtin_amdgcn_mfma_f32_16x16x32_bf16(a, b, acc[u], 0, 0, 0);
        }
    }
    int row0 = rt * 16 + ((lane >> 4) << 2);
#pragma unroll
    for (int u = 0; u < CTW; ++u) {
        int col = (cg * CTW + u) * 16 + (lane & 15);
        float bi = (col < Nbias) ? bias[col] : 0.f;
        if (col < ncols) {
#pragma unroll
            for (int r = 0; r < 4; ++r) {
                int row = row0 + r;
                float v = acc[u][r] + bi;
                if (RELU) v = fmaxf(v, 0.f);
                if (OUTBF16) ((short*)Cout)[(size_t)row * ldc + col] = f2bf(v);
                else         ((float*)Cout)[(size_t)row * ldc + col] = v;
            }
        }
    }
}

extern "C" void kernel_launch(void* const* d_in, const int* in_sizes, int n_in,
                              void* d_out, int out_size, void* d_ws, size_t ws_size,
                              hipStream_t stream) {
    const float* x    = (const float*)d_in[0];
    const int*   ei   = (const int*)d_in[1];
    const int*   batch= (const int*)d_in[2];
    const float* W1   = (const float*)d_in[3];
    const float* b1   = (const float*)d_in[4];
    const float* W2   = (const float*)d_in[5];
    const float* b2   = (const float*)d_in[6];
    const float* Wf1  = (const float*)d_in[7];
    const float* bf1  = (const float*)d_in[8];
    const float* Wf2  = (const float*)d_in[9];
    const float* bf2  = (const float*)d_in[10];

    const int* src = ei;
    const int* dst = ei + NE;

    float* xg_out = (float*)d_out;                    // [NG, FO]
    float* h2     = (float*)d_out + (size_t)NG * FO;  // [NN, F2] fp32

    // workspace layout
    short* h1   = (short*)d_ws;                        // NN*96
    short* A3   = h1 + (size_t)NN * 96;                // NG*1696
    short* fc1o = A3 + (size_t)NG * 1696;              // NG*1024
    short* W1p  = fc1o + (size_t)NG * FH;              // S1*8
    short* W2p  = W1p + (size_t)S1 * 8;                // S2*8
    short* Wf1p = W2p + (size_t)S2 * 8;                // S3*8
    short* Wf2p = Wf1p + (size_t)S3 * 8;               // S4*8
    int*   deg  = (int*)(Wf2p + (size_t)S4 * 8);       // NN
    int*   cnt  = deg + NN;                            // NN
    int*   rowptr = cnt + NN;                          // NN+1
    int*   bsum = rowptr + NN + 1;                     // 128
    int*   eid  = bsum + 128;                          // NE
    float* Pmax = (float*)(eid + NE);                  // NT2*840
    float* Psum = Pmax + (size_t)NT2 * F2;             // NT2*840

    const int blk = 256;
    auto cdiv = [](long long a, long long b) { return (int)((a + b - 1) / b); };
    const int nb1024 = cdiv(NN, 1024);  // 98

    // ---- front: zero deg, then deg || pack ----
    hipMemsetAsync(deg, 0, (size_t)NN * sizeof(int), stream);
    front_kernel<<<NB_DEG + NB_PACK, blk, 0, stream>>>(
        dst, deg, W1, W1p, W2, W2p, Wf1, Wf1p, Wf2, Wf2p);

    // ---- CSR scan + fill ----
    scan_ph1<<<nb1024, 1024, 0, stream>>>(deg, rowptr, bsum);
    scan_ph23<<<nb1024, 1024, 0, stream>>>(rowptr, bsum, cnt, nb1024);
    edge_fill<<<cdiv(NE, blk), blk, 0, stream>>>(src, dst, rowptr, cnt, eid);

    // ---- conv1 (fp32 gather direct from x, eid staged in LDS) ----
    conv1_f32<<<NT2, 256, 0, stream>>>(x, rowptr, eid, W1p, b1, h1);

    // ---- conv2 (8 waves x CTW=7, 2 row-tiles/block, eid staged in LDS) ----
    conv2_part<<<NT2 / 2, 512, 0, stream>>>(h1, rowptr, eid, W2p, b2, h2, Pmax, Psum);

    // ---- pooling from partials + boundary rows ----
    pool_kernel<<<NG, blk, 0, stream>>>(h2, batch, Pmax, Psum, A3);

    // ---- fc head ----
    gemmN<2, true, true><<<cdiv(125LL * 32 * 64, blk), blk, 0, stream>>>(
        A3, Wf1p, bf1, fc1o, 1696, FH, FH, FH, 125, 32);
    gemmN<2, false, false><<<cdiv(125LL * 12 * 64, blk), blk, 0, stream>>>(
        fc1o, Wf2p, bf2, xg_out, 1024, FO, FO, FO, 125, 12);
}